// Round 11
// baseline (674.608 us; speedup 1.0000x reference)
//
#include <hip/hip_runtime.h>
#include <hip/hip_bf16.h>
#include <stdint.h>

// Fused causal MHA, B=256,T=128,H=8,D=256,C=256. One block per (h,b).
// Round 11: round-10 structure with the Ph2 indexing bug fixed:
// per e-half, s-columns are split across nh (groups nh*4+nt), no p-loop.
// LDS 68.6KB (2 blocks/CU target), __launch_bounds__(512,4).

#define TT 128

typedef __attribute__((ext_vector_type(8))) short short8;
typedef __attribute__((ext_vector_type(4))) float f32x4;

// ---- ws map (total 18948128 B < proven-available 20054016) ----
#define WS_X    0u                       // 256 b x 64KB  X A/B-frags
#define WS_M    16777216u                // 8 h x 128KB   M^T-layout B-frags (scaled 1/16)
#define WS_WM   17825792u                // 8 h x 128KB   WM A-frags
#define WS_WB   18874368u                // 8 h x 8KB     [w2;w1] B-frags (rows 0,1), zero-filled
#define WS_BB   18939904u                // 8 h x 1KB     bb fp32
#define WS_CQ   18948096u                // 8 x 4B        cqk fp32

// ---- LDS map (68608 B -> 2 blocks/CU) ----
#define R_A    0        // T1-half [128t][256B swz] -> P [128t][256B swz]
#define R_B    32768    // H-half  [128e][256B swz]
#define R_UV   65536    // v[128] f32 | u[128] f32
#define R_RED  66560    // redM[256] | redS[256]
#define LDS_SIZE 68608

#define LGKM0()  asm volatile("s_waitcnt lgkmcnt(0)" ::: "memory")
#define BAR()    do { asm volatile("" ::: "memory"); __builtin_amdgcn_s_barrier(); asm volatile("" ::: "memory"); } while (0)
#define PRIO1()  __builtin_amdgcn_s_setprio(1)
#define PRIO0()  __builtin_amdgcn_s_setprio(0)

__device__ __forceinline__ unsigned short f2bf(float x) {
    union { float f; unsigned u; } v; v.f = x;
    unsigned r = v.u + 0x7FFFu + ((v.u >> 16) & 1u);
    return (unsigned short)(r >> 16);
}
__device__ __forceinline__ unsigned pk2(float a, float b) {
    return (unsigned)f2bf(a) | ((unsigned)f2bf(b) << 16);
}

// =============== convert / fold kernel (unchanged from round 9) ============
__global__ __launch_bounds__(256) void convert_pre(
    const float* __restrict__ x,
    const float* __restrict__ Wq, const float* __restrict__ bq,
    const float* __restrict__ Wk, const float* __restrict__ bk,
    const float* __restrict__ Wv, const float* __restrict__ bv,
    const float* __restrict__ Wp, const float* __restrict__ bp,
    char* __restrict__ ws)
{
    extern __shared__ char clds[];
    const int tid = threadIdx.x;
    const int bid = blockIdx.x;

    if (bid < 256) {
        const float* src = x + (size_t)bid * 32768;
        char* dst = ws + WS_X + (size_t)bid * 65536;
        for (int i = tid; i < 8192; i += 256) {
            float4 v = ((const float4*)src)[i];
            int row = i >> 6, c4 = i & 63;
            uint2 u; u.x = pk2(v.x, v.y); u.y = pk2(v.z, v.w);
            *(uint2*)(clds + row * 512 + ((c4 * 8) ^ ((row & 7) << 4))) = u;
        }
        __syncthreads();
        for (int i = tid; i < 4096; i += 256) {
            int l = i & 63, ks = (i >> 6) & 7, g = i >> 9;
            int r = g * 16 + (l & 15);
            int boff = ks * 64 + (l >> 4) * 16;
            uint4 q = *(const uint4*)(clds + r * 512 + (boff ^ ((r & 7) << 4)));
            ((uint4*)dst)[i] = q;
        }
        return;
    }
    if (bid < 384) {
        int id = bid - 256, h = id >> 4, st = id & 15;
        float* wkL = (float*)clds;
        for (int i = tid; i < 4096; i += 256) {
            int d = i >> 4, cc = i & 15;
            wkL[i] = Wk[(size_t)h * 65536 + d * 256 + st * 16 + cc];
        }
        __syncthreads();
        const int c = tid;
        float acc[16];
        #pragma unroll
        for (int j = 0; j < 16; ++j) acc[j] = 0.f;
        #pragma unroll 4
        for (int d = 0; d < 256; ++d) {
            float a = Wq[(size_t)h * 65536 + d * 256 + c];
            #pragma unroll
            for (int j = 0; j < 16; ++j) acc[j] += a * wkL[d * 16 + j];
        }
        char* base = ws + WS_M + (size_t)h * 131072;
        int ks = c >> 5, lgp = (c >> 3) & 3, jb = c & 7;
        #pragma unroll
        for (int j = 0; j < 16; ++j) {
            int cp = st * 16 + j;
            *(unsigned short*)(base + (((st * 8 + ks)) << 10)
                + ((cp & 15) + 16 * lgp) * 16 + jb * 2) = f2bf(acc[j] * 0.0625f);
        }
        return;
    }
    if (bid < 512) {
        int id = bid - 384, h = id >> 4, st = id & 15;
        float* wpL = (float*)clds;
        for (int i = tid; i < 4096; i += 256) {
            int e = i >> 8, d = i & 255;
            wpL[e * 257 + d] = Wp[(size_t)(st * 16 + e) * 256 + d];
        }
        __syncthreads();
        const int c = tid;
        float acc[16];
        #pragma unroll
        for (int j = 0; j < 16; ++j) acc[j] = 0.f;
        #pragma unroll 4
        for (int d = 0; d < 256; ++d) {
            float wv = Wv[(size_t)h * 65536 + d * 256 + c];
            #pragma unroll
            for (int j = 0; j < 16; ++j) acc[j] += wv * wpL[j * 257 + d];
        }
        char* base = ws + WS_WM + (size_t)h * 131072;
        int ks = c >> 5, lgp = (c >> 3) & 3, jb = c & 7;
        #pragma unroll
        for (int j = 0; j < 16; ++j) {
            *(unsigned short*)(base + (((st * 8 + ks)) << 10)
                + (j + 16 * lgp) * 16 + jb * 2) = f2bf(acc[j]);
        }
        return;
    }
    if (bid < 520) {
        const int h = bid - 512;
        {
            uint4 z = {0u,0u,0u,0u};
            for (int i = tid; i < 512; i += 256)
                ((uint4*)(ws + WS_WB + (size_t)h * 8192))[i] = z;
        }
        float* tK = (float*)clds;
        float* tQ = (float*)(clds + 16384);
        const int c = tid;
        float s1 = 0.f, s2 = 0.f;
        for (int d0 = 0; d0 < 256; d0 += 16) {
            __syncthreads();
            for (int i = tid; i < 1024; i += 256) {
                int row = i >> 6, c4 = i & 63;
                ((float4*)tK)[row * 64 + c4] =
                    ((const float4*)(Wk + (size_t)h * 65536 + (size_t)(d0 + row) * 256))[c4];
                ((float4*)tQ)[row * 64 + c4] =
                    ((const float4*)(Wq + (size_t)h * 65536 + (size_t)(d0 + row) * 256))[c4];
            }
            __syncthreads();
            #pragma unroll
            for (int dd = 0; dd < 16; ++dd) {
                s1 += tK[dd * 256 + c] * bq[h * 256 + d0 + dd];
                s2 += tQ[dd * 256 + c] * bk[h * 256 + d0 + dd];
            }
        }
        int ks = c >> 5, lgp = (c >> 3) & 3, jb = c & 7;
        char* base = ws + WS_WB + (size_t)h * 8192 + ks * 1024;
        *(unsigned short*)(base + (0 + 16 * lgp) * 16 + jb * 2) = f2bf(s2 * 0.0625f);
        *(unsigned short*)(base + (1 + 16 * lgp) * 16 + jb * 2) = f2bf(s1 * 0.0625f);
        float* red = (float*)(clds + 32768);
        red[tid] = bq[h * 256 + tid] * bk[h * 256 + tid];
        __syncthreads();
        if (tid == 0) {
            float cq = 0.f;
            for (int d = 0; d < 256; ++d) cq += red[d];
            *(float*)(ws + WS_CQ + h * 4) = cq * 0.0625f;
        }
        return;
    }
    {
        const int st = bid - 520;
        float* wpT = (float*)clds;
        float* bvL = (float*)(clds + 17408);
        for (int i = tid; i < 1024; i += 256) {
            int row = i >> 6, c4 = i & 63;
            float4 v = ((const float4*)(Wp + (size_t)(st * 16 + row) * 256))[c4];
            float* dstp = wpT + row * 257 + c4 * 4;
            dstp[0] = v.x; dstp[1] = v.y; dstp[2] = v.z; dstp[3] = v.w;
        }
        for (int i = tid; i < 512; i += 256)
            ((float4*)bvL)[i] = ((const float4*)bv)[i];
        __syncthreads();
        const int el = tid >> 4, dg = tid & 15;
        #pragma unroll
        for (int h = 0; h < 8; ++h) {
            float p = 0.f;
            #pragma unroll
            for (int dd = 0; dd < 16; ++dd) {
                int d = dg * 16 + dd;
                p += bvL[h * 256 + d] * wpT[el * 257 + d];
            }
            p += __shfl_xor(p, 1);
            p += __shfl_xor(p, 2);
            p += __shfl_xor(p, 4);
            p += __shfl_xor(p, 8);
            if (dg == 0)
                *(float*)(ws + WS_BB + (size_t)h * 1024 + (st * 16 + el) * 4)
                    = bp[st * 16 + el] + p;
        }
        return;
    }
}

// =============== main fused kernel =========================================
__global__ __launch_bounds__(512, 4) void mha_fused(
    const char* __restrict__ ws, float* __restrict__ out)
{
    extern __shared__ char lds[];
    const int tid = threadIdx.x;
    const int w  = tid >> 6, l = tid & 63;
    const int lg = l >> 4, lr = l & 15;
    const int mq = w & 3, nh = w >> 2;      // 4 M-waves x 2 N-waves
    const int bid = blockIdx.x;
    const int h = bid >> 8, b = bid & 255;

    const char* Xf  = ws + WS_X  + (size_t)b * 65536;
    const char* Mh  = ws + WS_M  + (size_t)h * 131072;
    const char* WMh = ws + WS_WM + (size_t)h * 131072;
    const char* WBh = ws + WS_WB + (size_t)h * 8192;

    // X A-frags (row-groups mq*2+mt)
    short8 xf[2][8];
    #pragma unroll
    for (int mt = 0; mt < 2; ++mt)
        #pragma unroll
        for (int ks = 0; ks < 8; ++ks)
            xf[mt][ks] = *(const short8*)(Xf + (((mq*2 + mt)*8 + ks) << 10) + l*16);

    // ---- Ph0a: [v|u] = X * [w2;w1]^T ----
    {
        f32x4 vacc[2] = {f32x4{0.f,0.f,0.f,0.f}, f32x4{0.f,0.f,0.f,0.f}};
        #pragma unroll
        for (int ks = 0; ks < 8; ++ks) {
            short8 wb = *(const short8*)(WBh + (ks << 10) + l*16);
            vacc[0] = __builtin_amdgcn_mfma_f32_16x16x32_bf16(xf[0][ks], wb, vacc[0], 0, 0, 0);
            vacc[1] = __builtin_amdgcn_mfma_f32_16x16x32_bf16(xf[1][ks], wb, vacc[1], 0, 0, 0);
        }
        if (nh == 0 && lr < 2) {
            #pragma unroll
            for (int mt = 0; mt < 2; ++mt)
                #pragma unroll
                for (int r = 0; r < 4; ++r) {
                    int t = mq*32 + mt*16 + lg*4 + r;
                    *(float*)(lds + R_UV + lr*512 + t*4) = vacc[mt][r];
                }
        }
    }

    // ---- Ph0b/Ph1: T1 halves (128 cols) -> S accumulation ----
    f32x4 sacc[2][4];
    #pragma unroll
    for (int i = 0; i < 2; ++i)
        #pragma unroll
        for (int j = 0; j < 4; ++j) sacc[i][j] = f32x4{0.f,0.f,0.f,0.f};

    #pragma unroll
    for (int h2 = 0; h2 < 2; ++h2) {
        // T1h = X * N[:, half] -> R_A  [128t][256B swz]
        const int ga = h2*8 + nh*4;
        f32x4 acc[2][4];
        #pragma unroll
        for (int i = 0; i < 2; ++i)
            #pragma unroll
            for (int j = 0; j < 4; ++j) acc[i][j] = f32x4{0.f,0.f,0.f,0.f};
        #pragma unroll
        for (int ks = 0; ks < 8; ++ks) {
            short8 nb[4];
            #pragma unroll
            for (int nt = 0; nt < 4; ++nt)
                nb[nt] = *(const short8*)(Mh + (((ga+nt)*8 + ks) << 10) + l*16);
            PRIO1();
            #pragma unroll
            for (int mt = 0; mt < 2; ++mt)
                #pragma unroll
                for (int nt = 0; nt < 4; ++nt)
                    acc[mt][nt] = __builtin_amdgcn_mfma_f32_16x16x32_bf16(xf[mt][ks], nb[nt], acc[mt][nt], 0, 0, 0);
            PRIO0();
        }
        #pragma unroll
        for (int mt = 0; mt < 2; ++mt)
            #pragma unroll
            for (int nt = 0; nt < 4; ++nt)
                #pragma unroll
                for (int r = 0; r < 4; ++r) {
                    int t = mq*32 + mt*16 + lg*4 + r;
                    int cpl = (nh*4+nt)*16 + lr;     // col within half
                    *(unsigned short*)(lds + R_A + t*256 + ((cpl*2) ^ ((t&7)<<4)))
                        = f2bf(acc[mt][nt][r]);
                }
        LGKM0(); BAR();
        // S += T1h * X[:, half]^T
        #pragma unroll
        for (int ks2 = 0; ks2 < 4; ++ks2) {
            short8 ta[2];
            #pragma unroll
            for (int mt = 0; mt < 2; ++mt) {
                int t2 = mq*32 + mt*16 + lr;
                ta[mt] = *(const short8*)(lds + R_A + t2*256 + ((ks2*64 + lg*16) ^ ((t2&7)<<4)));
            }
            short8 sb[4];
            #pragma unroll
            for (int nt = 0; nt < 4; ++nt)
                sb[nt] = *(const short8*)(Xf + (((nh*4+nt)*8 + (h2*4+ks2)) << 10) + l*16);
            PRIO1();
            #pragma unroll
            for (int mt = 0; mt < 2; ++mt)
                #pragma unroll
                for (int nt = 0; nt < 4; ++nt)
                    sacc[mt][nt] = __builtin_amdgcn_mfma_f32_16x16x32_bf16(ta[mt], sb[nt], sacc[mt][nt], 0, 0, 0);
            PRIO0();
        }
        if (h2 == 0) { LGKM0(); BAR(); }   // protect R_A overwrite
    }

    // ---- softmax: bias add, mask, max, exp, sum, P -> R_A ----
    {
        const float cq = *(const float*)(ws + WS_CQ + h*4);
        float uu[4];
        #pragma unroll
        for (int nt = 0; nt < 4; ++nt)
            uu[nt] = *(const float*)(lds + R_UV + 512 + (nh*64 + nt*16 + lr)*4);
        float* redM = (float*)(lds + R_RED);
        float* redS = redM + 256;
        float rmax[2][4];
        #pragma unroll
        for (int mt = 0; mt < 2; ++mt)
            #pragma unroll
            for (int r = 0; r < 4; ++r) {
                int t = mq*32 + mt*16 + lg*4 + r;
                float vt = *(const float*)(lds + R_UV + t*4) + cq;
                float m = -1e30f;
                #pragma unroll
                for (int nt = 0; nt < 4; ++nt) {
                    int s = nh*64 + nt*16 + lr;
                    float sv = sacc[mt][nt][r] + vt + uu[nt];
                    if (s > t) sv = -1e30f;
                    sacc[mt][nt][r] = sv;
                    m = fmaxf(m, sv);
                }
                m = fmaxf(m, __shfl_xor(m, 1));
                m = fmaxf(m, __shfl_xor(m, 2));
                m = fmaxf(m, __shfl_xor(m, 4));
                m = fmaxf(m, __shfl_xor(m, 8));
                rmax[mt][r] = m;
            }
        if (lr == 0) {
            #pragma unroll
            for (int mt = 0; mt < 2; ++mt)
                #pragma unroll
                for (int r = 0; r < 4; ++r)
                    redM[nh*128 + mq*32 + mt*16 + lg*4 + r] = rmax[mt][r];
        }
        LGKM0(); BAR();
        float rsum[2][4];
        #pragma unroll
        for (int mt = 0; mt < 2; ++mt)
            #pragma unroll
            for (int r = 0; r < 4; ++r) {
                int t = mq*32 + mt*16 + lg*4 + r;
                float m = fmaxf(redM[t], redM[128 + t]);
                float ssum = 0.f;
                #pragma unroll
                for (int nt = 0; nt < 4; ++nt) {
                    float p = __expf(sacc[mt][nt][r] - m);
                    sacc[mt][nt][r] = p;
                    ssum += p;
                }
                ssum += __shfl_xor(ssum, 1);
                ssum += __shfl_xor(ssum, 2);
                ssum += __shfl_xor(ssum, 4);
                ssum += __shfl_xor(ssum, 8);
                rsum[mt][r] = ssum;
            }
        if (lr == 0) {
            #pragma unroll
            for (int mt = 0; mt < 2; ++mt)
                #pragma unroll
                for (int r = 0; r < 4; ++r)
                    redS[nh*128 + mq*32 + mt*16 + lg*4 + r] = rsum[mt][r];
        }
        LGKM0(); BAR();
        #pragma unroll
        for (int mt = 0; mt < 2; ++mt)
            #pragma unroll
            for (int r = 0; r < 4; ++r) {
                int t = mq*32 + mt*16 + lg*4 + r;
                float inv = 1.0f / (redS[t] + redS[128 + t]);
                #pragma unroll
                for (int nt = 0; nt < 4; ++nt) {
                    int s = nh*64 + nt*16 + lr;
                    *(unsigned short*)(lds + R_A + t*256 + ((s*2) ^ ((t&7)<<4)))
                        = f2bf(sacc[mt][nt][r] * inv);
                }
            }
    }
    LGKM0(); BAR();

    // P A-frags (live through both e-halves)
    short8 pa[2][4];
    #pragma unroll
    for (int mt = 0; mt < 2; ++mt) {
        int t2 = mq*32 + mt*16 + lr;
        #pragma unroll
        for (int ks = 0; ks < 4; ++ks)
            pa[mt][ks] = *(const short8*)(lds + R_A + t2*256 + ((ks*64 + lg*16) ^ ((t2&7)<<4)));
    }

    // ---- Ph2/Ph3: H halves (128 rows) -> OUT e-halves ----
    const float* bbp = (const float*)(ws + WS_BB + h*1024);
    #pragma unroll
    for (int eh = 0; eh < 2; ++eh) {
        // Hh = WM[eh half rows] * X^T -> R_B [128e local][128s], swz
        // wave covers: e local (mq*2+me)*16, s = (nh*4+nt)*16 (s split by nh)
        {
            f32x4 acc[2][4];
            #pragma unroll
            for (int i = 0; i < 2; ++i)
                #pragma unroll
                for (int j = 0; j < 4; ++j) acc[i][j] = f32x4{0.f,0.f,0.f,0.f};
            #pragma unroll
            for (int ks = 0; ks < 8; ++ks) {
                short8 wa[2];
                #pragma unroll
                for (int me = 0; me < 2; ++me)
                    wa[me] = *(const short8*)(WMh + (((eh*8 + mq*2+me)*8 + ks) << 10) + l*16);
                short8 sb[4];
                #pragma unroll
                for (int nt = 0; nt < 4; ++nt)
                    sb[nt] = *(const short8*)(Xf + (((nh*4 + nt)*8 + ks) << 10) + l*16);
                PRIO1();
                #pragma unroll
                for (int me = 0; me < 2; ++me)
                    #pragma unroll
                    for (int nt = 0; nt < 4; ++nt)
                        acc[me][nt] = __builtin_amdgcn_mfma_f32_16x16x32_bf16(wa[me], sb[nt], acc[me][nt], 0, 0, 0);
                PRIO0();
            }
            #pragma unroll
            for (int me = 0; me < 2; ++me)
                #pragma unroll
                for (int nt = 0; nt < 4; ++nt)
                    #pragma unroll
                    for (int r = 0; r < 4; ++r) {
                        int el = (mq*2+me)*16 + lg*4 + r;
                        int s  = (nh*4 + nt)*16 + lr;
                        *(unsigned short*)(lds + R_B + el*256 + ((s*2) ^ ((el&7)<<4)))
                            = f2bf(acc[me][nt][r]);
                    }
        }
        LGKM0(); BAR();
        // OUT[:, e-half] = P * Hh^T + bb
        #pragma unroll
        for (int ec = 0; ec < 2; ++ec) {
            f32x4 acc[2][2];
            #pragma unroll
            for (int i = 0; i < 2; ++i)
                #pragma unroll
                for (int j = 0; j < 2; ++j) acc[i][j] = f32x4{0.f,0.f,0.f,0.f};
            #pragma unroll
            for (int ks = 0; ks < 4; ++ks) {
                short8 hb[2];
                #pragma unroll
                for (int nt = 0; nt < 2; ++nt) {
                    int erl = (nh*4 + ec*2 + nt)*16 + lr;
                    hb[nt] = *(const short8*)(lds + R_B + erl*256 + ((ks*64 + lg*16) ^ ((erl&7)<<4)));
                }
                PRIO1();
                #pragma unroll
                for (int mt = 0; mt < 2; ++mt)
                    #pragma unroll
                    for (int nt = 0; nt < 2; ++nt)
                        acc[mt][nt] = __builtin_amdgcn_mfma_f32_16x16x32_bf16(pa[mt][ks], hb[nt], acc[mt][nt], 0, 0, 0);
                PRIO0();
            }
            #pragma unroll
            for (int nt = 0; nt < 2; ++nt) {
                int e = eh*128 + (nh*4 + ec*2 + nt)*16 + lr;
                float bbv = bbp[e];
                #pragma unroll
                for (int mt = 0; mt < 2; ++mt)
                    #pragma unroll
                    for (int r = 0; r < 4; ++r) {
                        int t = mq*32 + mt*16 + lg*4 + r;
                        out[((size_t)bid * TT + t) * 256 + e] = acc[mt][nt][r] + bbv;
                    }
            }
        }
        if (eh == 0) { LGKM0(); BAR(); }   // protect R_B overwrite
    }
}

extern "C" void kernel_launch(void* const* d_in, const int* in_sizes, int n_in,
                              void* d_out, int out_size, void* d_ws, size_t ws_size,
                              hipStream_t stream) {
    (void)in_sizes; (void)n_in; (void)out_size; (void)ws_size; // needs ws_size >= 18948128
    const float* x  = (const float*)d_in[0];
    const float* Wq = (const float*)d_in[1];
    const float* bq = (const float*)d_in[2];
    const float* Wk = (const float*)d_in[3];
    const float* bk = (const float*)d_in[4];
    const float* Wv = (const float*)d_in[5];
    const float* bv = (const float*)d_in[6];
    const float* Wp = (const float*)d_in[7];
    const float* bp = (const float*)d_in[8];
    char* ws = (char*)d_ws;

    hipFuncSetAttribute((const void*)convert_pre,
                        hipFuncAttributeMaxDynamicSharedMemorySize, 65536);
    convert_pre<<<dim3(536), dim3(256), 65536, stream>>>(
        x, Wq, bq, Wk, bk, Wv, bv, Wp, bp, ws);

    hipFuncSetAttribute((const void*)mha_fused,
                        hipFuncAttributeMaxDynamicSharedMemorySize, LDS_SIZE);
    mha_fused<<<dim3(2048), dim3(512), LDS_SIZE, stream>>>(ws, (float*)d_out);
}

// Round 12
// 321.451 us; speedup vs baseline: 2.0986x; 2.0986x over previous
//
#include <hip/hip_runtime.h>
#include <hip/hip_bf16.h>
#include <stdint.h>

// Fused causal MHA, B=256,T=128,H=8,D=256,C=256. One block per (h,b).
// Round 12: round-11 kernel with launch bounds corrected to (512,2):
// 2 waves/SIMD/block target -> 128-VGPR cap (no spill), LDS 68.6KB
// -> 2 blocks/CU. (Round 11's (512,4) meant 32 waves/CU -> 64-reg spill.)

#define TT 128

typedef __attribute__((ext_vector_type(8))) short short8;
typedef __attribute__((ext_vector_type(4))) float f32x4;

// ---- ws map (total 18948128 B < proven-available 20054016) ----
#define WS_X    0u                       // 256 b x 64KB  X A/B-frags
#define WS_M    16777216u                // 8 h x 128KB   M^T-layout B-frags (scaled 1/16)
#define WS_WM   17825792u                // 8 h x 128KB   WM A-frags
#define WS_WB   18874368u                // 8 h x 8KB     [w2;w1] B-frags (rows 0,1), zero-filled
#define WS_BB   18939904u                // 8 h x 1KB     bb fp32
#define WS_CQ   18948096u                // 8 x 4B        cqk fp32

// ---- LDS map (68608 B -> 2 blocks/CU) ----
#define R_A    0        // T1-half [128t][256B swz] -> P [128t][256B swz]
#define R_B    32768    // H-half  [128e][256B swz]
#define R_UV   65536    // v[128] f32 | u[128] f32
#define R_RED  66560    // redM[256] | redS[256]
#define LDS_SIZE 68608

#define LGKM0()  asm volatile("s_waitcnt lgkmcnt(0)" ::: "memory")
#define BAR()    do { asm volatile("" ::: "memory"); __builtin_amdgcn_s_barrier(); asm volatile("" ::: "memory"); } while (0)
#define PRIO1()  __builtin_amdgcn_s_setprio(1)
#define PRIO0()  __builtin_amdgcn_s_setprio(0)

__device__ __forceinline__ unsigned short f2bf(float x) {
    union { float f; unsigned u; } v; v.f = x;
    unsigned r = v.u + 0x7FFFu + ((v.u >> 16) & 1u);
    return (unsigned short)(r >> 16);
}
__device__ __forceinline__ unsigned pk2(float a, float b) {
    return (unsigned)f2bf(a) | ((unsigned)f2bf(b) << 16);
}

// =============== convert / fold kernel (unchanged from round 9) ============
__global__ __launch_bounds__(256) void convert_pre(
    const float* __restrict__ x,
    const float* __restrict__ Wq, const float* __restrict__ bq,
    const float* __restrict__ Wk, const float* __restrict__ bk,
    const float* __restrict__ Wv, const float* __restrict__ bv,
    const float* __restrict__ Wp, const float* __restrict__ bp,
    char* __restrict__ ws)
{
    extern __shared__ char clds[];
    const int tid = threadIdx.x;
    const int bid = blockIdx.x;

    if (bid < 256) {
        const float* src = x + (size_t)bid * 32768;
        char* dst = ws + WS_X + (size_t)bid * 65536;
        for (int i = tid; i < 8192; i += 256) {
            float4 v = ((const float4*)src)[i];
            int row = i >> 6, c4 = i & 63;
            uint2 u; u.x = pk2(v.x, v.y); u.y = pk2(v.z, v.w);
            *(uint2*)(clds + row * 512 + ((c4 * 8) ^ ((row & 7) << 4))) = u;
        }
        __syncthreads();
        for (int i = tid; i < 4096; i += 256) {
            int l = i & 63, ks = (i >> 6) & 7, g = i >> 9;
            int r = g * 16 + (l & 15);
            int boff = ks * 64 + (l >> 4) * 16;
            uint4 q = *(const uint4*)(clds + r * 512 + (boff ^ ((r & 7) << 4)));
            ((uint4*)dst)[i] = q;
        }
        return;
    }
    if (bid < 384) {
        int id = bid - 256, h = id >> 4, st = id & 15;
        float* wkL = (float*)clds;
        for (int i = tid; i < 4096; i += 256) {
            int d = i >> 4, cc = i & 15;
            wkL[i] = Wk[(size_t)h * 65536 + d * 256 + st * 16 + cc];
        }
        __syncthreads();
        const int c = tid;
        float acc[16];
        #pragma unroll
        for (int j = 0; j < 16; ++j) acc[j] = 0.f;
        #pragma unroll 4
        for (int d = 0; d < 256; ++d) {
            float a = Wq[(size_t)h * 65536 + d * 256 + c];
            #pragma unroll
            for (int j = 0; j < 16; ++j) acc[j] += a * wkL[d * 16 + j];
        }
        char* base = ws + WS_M + (size_t)h * 131072;
        int ks = c >> 5, lgp = (c >> 3) & 3, jb = c & 7;
        #pragma unroll
        for (int j = 0; j < 16; ++j) {
            int cp = st * 16 + j;
            *(unsigned short*)(base + (((st * 8 + ks)) << 10)
                + ((cp & 15) + 16 * lgp) * 16 + jb * 2) = f2bf(acc[j] * 0.0625f);
        }
        return;
    }
    if (bid < 512) {
        int id = bid - 384, h = id >> 4, st = id & 15;
        float* wpL = (float*)clds;
        for (int i = tid; i < 4096; i += 256) {
            int e = i >> 8, d = i & 255;
            wpL[e * 257 + d] = Wp[(size_t)(st * 16 + e) * 256 + d];
        }
        __syncthreads();
        const int c = tid;
        float acc[16];
        #pragma unroll
        for (int j = 0; j < 16; ++j) acc[j] = 0.f;
        #pragma unroll 4
        for (int d = 0; d < 256; ++d) {
            float wv = Wv[(size_t)h * 65536 + d * 256 + c];
            #pragma unroll
            for (int j = 0; j < 16; ++j) acc[j] += wv * wpL[j * 257 + d];
        }
        char* base = ws + WS_WM + (size_t)h * 131072;
        int ks = c >> 5, lgp = (c >> 3) & 3, jb = c & 7;
        #pragma unroll
        for (int j = 0; j < 16; ++j) {
            *(unsigned short*)(base + (((st * 8 + ks)) << 10)
                + (j + 16 * lgp) * 16 + jb * 2) = f2bf(acc[j]);
        }
        return;
    }
    if (bid < 520) {
        const int h = bid - 512;
        {
            uint4 z = {0u,0u,0u,0u};
            for (int i = tid; i < 512; i += 256)
                ((uint4*)(ws + WS_WB + (size_t)h * 8192))[i] = z;
        }
        float* tK = (float*)clds;
        float* tQ = (float*)(clds + 16384);
        const int c = tid;
        float s1 = 0.f, s2 = 0.f;
        for (int d0 = 0; d0 < 256; d0 += 16) {
            __syncthreads();
            for (int i = tid; i < 1024; i += 256) {
                int row = i >> 6, c4 = i & 63;
                ((float4*)tK)[row * 64 + c4] =
                    ((const float4*)(Wk + (size_t)h * 65536 + (size_t)(d0 + row) * 256))[c4];
                ((float4*)tQ)[row * 64 + c4] =
                    ((const float4*)(Wq + (size_t)h * 65536 + (size_t)(d0 + row) * 256))[c4];
            }
            __syncthreads();
            #pragma unroll
            for (int dd = 0; dd < 16; ++dd) {
                s1 += tK[dd * 256 + c] * bq[h * 256 + d0 + dd];
                s2 += tQ[dd * 256 + c] * bk[h * 256 + d0 + dd];
            }
        }
        int ks = c >> 5, lgp = (c >> 3) & 3, jb = c & 7;
        char* base = ws + WS_WB + (size_t)h * 8192 + ks * 1024;
        *(unsigned short*)(base + (0 + 16 * lgp) * 16 + jb * 2) = f2bf(s2 * 0.0625f);
        *(unsigned short*)(base + (1 + 16 * lgp) * 16 + jb * 2) = f2bf(s1 * 0.0625f);
        float* red = (float*)(clds + 32768);
        red[tid] = bq[h * 256 + tid] * bk[h * 256 + tid];
        __syncthreads();
        if (tid == 0) {
            float cq = 0.f;
            for (int d = 0; d < 256; ++d) cq += red[d];
            *(float*)(ws + WS_CQ + h * 4) = cq * 0.0625f;
        }
        return;
    }
    {
        const int st = bid - 520;
        float* wpT = (float*)clds;
        float* bvL = (float*)(clds + 17408);
        for (int i = tid; i < 1024; i += 256) {
            int row = i >> 6, c4 = i & 63;
            float4 v = ((const float4*)(Wp + (size_t)(st * 16 + row) * 256))[c4];
            float* dstp = wpT + row * 257 + c4 * 4;
            dstp[0] = v.x; dstp[1] = v.y; dstp[2] = v.z; dstp[3] = v.w;
        }
        for (int i = tid; i < 512; i += 256)
            ((float4*)bvL)[i] = ((const float4*)bv)[i];
        __syncthreads();
        const int el = tid >> 4, dg = tid & 15;
        #pragma unroll
        for (int h = 0; h < 8; ++h) {
            float p = 0.f;
            #pragma unroll
            for (int dd = 0; dd < 16; ++dd) {
                int d = dg * 16 + dd;
                p += bvL[h * 256 + d] * wpT[el * 257 + d];
            }
            p += __shfl_xor(p, 1);
            p += __shfl_xor(p, 2);
            p += __shfl_xor(p, 4);
            p += __shfl_xor(p, 8);
            if (dg == 0)
                *(float*)(ws + WS_BB + (size_t)h * 1024 + (st * 16 + el) * 4)
                    = bp[st * 16 + el] + p;
        }
        return;
    }
}

// =============== main fused kernel =========================================
__global__ __launch_bounds__(512, 2) void mha_fused(
    const char* __restrict__ ws, float* __restrict__ out)
{
    extern __shared__ char lds[];
    const int tid = threadIdx.x;
    const int w  = tid >> 6, l = tid & 63;
    const int lg = l >> 4, lr = l & 15;
    const int mq = w & 3, nh = w >> 2;      // 4 M-waves x 2 N-waves
    const int bid = blockIdx.x;
    const int h = bid >> 8, b = bid & 255;

    const char* Xf  = ws + WS_X  + (size_t)b * 65536;
    const char* Mh  = ws + WS_M  + (size_t)h * 131072;
    const char* WMh = ws + WS_WM + (size_t)h * 131072;
    const char* WBh = ws + WS_WB + (size_t)h * 8192;

    // X A-frags (row-groups mq*2+mt)
    short8 xf[2][8];
    #pragma unroll
    for (int mt = 0; mt < 2; ++mt)
        #pragma unroll
        for (int ks = 0; ks < 8; ++ks)
            xf[mt][ks] = *(const short8*)(Xf + (((mq*2 + mt)*8 + ks) << 10) + l*16);

    // ---- Ph0a: [v|u] = X * [w2;w1]^T ----
    {
        f32x4 vacc[2] = {f32x4{0.f,0.f,0.f,0.f}, f32x4{0.f,0.f,0.f,0.f}};
        #pragma unroll
        for (int ks = 0; ks < 8; ++ks) {
            short8 wb = *(const short8*)(WBh + (ks << 10) + l*16);
            vacc[0] = __builtin_amdgcn_mfma_f32_16x16x32_bf16(xf[0][ks], wb, vacc[0], 0, 0, 0);
            vacc[1] = __builtin_amdgcn_mfma_f32_16x16x32_bf16(xf[1][ks], wb, vacc[1], 0, 0, 0);
        }
        if (nh == 0 && lr < 2) {
            #pragma unroll
            for (int mt = 0; mt < 2; ++mt)
                #pragma unroll
                for (int r = 0; r < 4; ++r) {
                    int t = mq*32 + mt*16 + lg*4 + r;
                    *(float*)(lds + R_UV + lr*512 + t*4) = vacc[mt][r];
                }
        }
    }

    // ---- Ph0b/Ph1: T1 halves (128 cols) -> S accumulation ----
    f32x4 sacc[2][4];
    #pragma unroll
    for (int i = 0; i < 2; ++i)
        #pragma unroll
        for (int j = 0; j < 4; ++j) sacc[i][j] = f32x4{0.f,0.f,0.f,0.f};

    #pragma unroll
    for (int h2 = 0; h2 < 2; ++h2) {
        // T1h = X * N[:, half] -> R_A  [128t][256B swz]
        const int ga = h2*8 + nh*4;
        f32x4 acc[2][4];
        #pragma unroll
        for (int i = 0; i < 2; ++i)
            #pragma unroll
            for (int j = 0; j < 4; ++j) acc[i][j] = f32x4{0.f,0.f,0.f,0.f};
        #pragma unroll
        for (int ks = 0; ks < 8; ++ks) {
            short8 nb[4];
            #pragma unroll
            for (int nt = 0; nt < 4; ++nt)
                nb[nt] = *(const short8*)(Mh + (((ga+nt)*8 + ks) << 10) + l*16);
            PRIO1();
            #pragma unroll
            for (int mt = 0; mt < 2; ++mt)
                #pragma unroll
                for (int nt = 0; nt < 4; ++nt)
                    acc[mt][nt] = __builtin_amdgcn_mfma_f32_16x16x32_bf16(xf[mt][ks], nb[nt], acc[mt][nt], 0, 0, 0);
            PRIO0();
        }
        #pragma unroll
        for (int mt = 0; mt < 2; ++mt)
            #pragma unroll
            for (int nt = 0; nt < 4; ++nt)
                #pragma unroll
                for (int r = 0; r < 4; ++r) {
                    int t = mq*32 + mt*16 + lg*4 + r;
                    int cpl = (nh*4+nt)*16 + lr;     // col within half
                    *(unsigned short*)(lds + R_A + t*256 + ((cpl*2) ^ ((t&7)<<4)))
                        = f2bf(acc[mt][nt][r]);
                }
        LGKM0(); BAR();
        // S += T1h * X[:, half]^T
        #pragma unroll
        for (int ks2 = 0; ks2 < 4; ++ks2) {
            short8 ta[2];
            #pragma unroll
            for (int mt = 0; mt < 2; ++mt) {
                int t2 = mq*32 + mt*16 + lr;
                ta[mt] = *(const short8*)(lds + R_A + t2*256 + ((ks2*64 + lg*16) ^ ((t2&7)<<4)));
            }
            short8 sb[4];
            #pragma unroll
            for (int nt = 0; nt < 4; ++nt)
                sb[nt] = *(const short8*)(Xf + (((nh*4+nt)*8 + (h2*4+ks2)) << 10) + l*16);
            PRIO1();
            #pragma unroll
            for (int mt = 0; mt < 2; ++mt)
                #pragma unroll
                for (int nt = 0; nt < 4; ++nt)
                    sacc[mt][nt] = __builtin_amdgcn_mfma_f32_16x16x32_bf16(ta[mt], sb[nt], sacc[mt][nt], 0, 0, 0);
            PRIO0();
        }
        if (h2 == 0) { LGKM0(); BAR(); }   // protect R_A overwrite
    }

    // ---- softmax: bias add, mask, max, exp, sum, P -> R_A ----
    {
        const float cq = *(const float*)(ws + WS_CQ + h*4);
        float uu[4];
        #pragma unroll
        for (int nt = 0; nt < 4; ++nt)
            uu[nt] = *(const float*)(lds + R_UV + 512 + (nh*64 + nt*16 + lr)*4);
        float* redM = (float*)(lds + R_RED);
        float* redS = redM + 256;
        float rmax[2][4];
        #pragma unroll
        for (int mt = 0; mt < 2; ++mt)
            #pragma unroll
            for (int r = 0; r < 4; ++r) {
                int t = mq*32 + mt*16 + lg*4 + r;
                float vt = *(const float*)(lds + R_UV + t*4) + cq;
                float m = -1e30f;
                #pragma unroll
                for (int nt = 0; nt < 4; ++nt) {
                    int s = nh*64 + nt*16 + lr;
                    float sv = sacc[mt][nt][r] + vt + uu[nt];
                    if (s > t) sv = -1e30f;
                    sacc[mt][nt][r] = sv;
                    m = fmaxf(m, sv);
                }
                m = fmaxf(m, __shfl_xor(m, 1));
                m = fmaxf(m, __shfl_xor(m, 2));
                m = fmaxf(m, __shfl_xor(m, 4));
                m = fmaxf(m, __shfl_xor(m, 8));
                rmax[mt][r] = m;
            }
        if (lr == 0) {
            #pragma unroll
            for (int mt = 0; mt < 2; ++mt)
                #pragma unroll
                for (int r = 0; r < 4; ++r)
                    redM[nh*128 + mq*32 + mt*16 + lg*4 + r] = rmax[mt][r];
        }
        LGKM0(); BAR();
        float rsum[2][4];
        #pragma unroll
        for (int mt = 0; mt < 2; ++mt)
            #pragma unroll
            for (int r = 0; r < 4; ++r) {
                int t = mq*32 + mt*16 + lg*4 + r;
                float m = fmaxf(redM[t], redM[128 + t]);
                float ssum = 0.f;
                #pragma unroll
                for (int nt = 0; nt < 4; ++nt) {
                    float p = __expf(sacc[mt][nt][r] - m);
                    sacc[mt][nt][r] = p;
                    ssum += p;
                }
                ssum += __shfl_xor(ssum, 1);
                ssum += __shfl_xor(ssum, 2);
                ssum += __shfl_xor(ssum, 4);
                ssum += __shfl_xor(ssum, 8);
                rsum[mt][r] = ssum;
            }
        if (lr == 0) {
            #pragma unroll
            for (int mt = 0; mt < 2; ++mt)
                #pragma unroll
                for (int r = 0; r < 4; ++r)
                    redS[nh*128 + mq*32 + mt*16 + lg*4 + r] = rsum[mt][r];
        }
        LGKM0(); BAR();
        #pragma unroll
        for (int mt = 0; mt < 2; ++mt)
            #pragma unroll
            for (int r = 0; r < 4; ++r) {
                int t = mq*32 + mt*16 + lg*4 + r;
                float inv = 1.0f / (redS[t] + redS[128 + t]);
                #pragma unroll
                for (int nt = 0; nt < 4; ++nt) {
                    int s = nh*64 + nt*16 + lr;
                    *(unsigned short*)(lds + R_A + t*256 + ((s*2) ^ ((t&7)<<4)))
                        = f2bf(sacc[mt][nt][r] * inv);
                }
            }
    }
    LGKM0(); BAR();

    // P A-frags (live through both e-halves)
    short8 pa[2][4];
    #pragma unroll
    for (int mt = 0; mt < 2; ++mt) {
        int t2 = mq*32 + mt*16 + lr;
        #pragma unroll
        for (int ks = 0; ks < 4; ++ks)
            pa[mt][ks] = *(const short8*)(lds + R_A + t2*256 + ((ks*64 + lg*16) ^ ((t2&7)<<4)));
    }

    // ---- Ph2/Ph3: H halves (128 rows) -> OUT e-halves ----
    const float* bbp = (const float*)(ws + WS_BB + h*1024);
    #pragma unroll
    for (int eh = 0; eh < 2; ++eh) {
        // Hh = WM[eh half rows] * X^T -> R_B [128e local][128s], swz
        {
            f32x4 acc[2][4];
            #pragma unroll
            for (int i = 0; i < 2; ++i)
                #pragma unroll
                for (int j = 0; j < 4; ++j) acc[i][j] = f32x4{0.f,0.f,0.f,0.f};
            #pragma unroll
            for (int ks = 0; ks < 8; ++ks) {
                short8 wa[2];
                #pragma unroll
                for (int me = 0; me < 2; ++me)
                    wa[me] = *(const short8*)(WMh + (((eh*8 + mq*2+me)*8 + ks) << 10) + l*16);
                short8 sb[4];
                #pragma unroll
                for (int nt = 0; nt < 4; ++nt)
                    sb[nt] = *(const short8*)(Xf + (((nh*4 + nt)*8 + ks) << 10) + l*16);
                PRIO1();
                #pragma unroll
                for (int me = 0; me < 2; ++me)
                    #pragma unroll
                    for (int nt = 0; nt < 4; ++nt)
                        acc[me][nt] = __builtin_amdgcn_mfma_f32_16x16x32_bf16(wa[me], sb[nt], acc[me][nt], 0, 0, 0);
                PRIO0();
            }
            #pragma unroll
            for (int me = 0; me < 2; ++me)
                #pragma unroll
                for (int nt = 0; nt < 4; ++nt)
                    #pragma unroll
                    for (int r = 0; r < 4; ++r) {
                        int el = (mq*2+me)*16 + lg*4 + r;
                        int s  = (nh*4 + nt)*16 + lr;
                        *(unsigned short*)(lds + R_B + el*256 + ((s*2) ^ ((el&7)<<4)))
                            = f2bf(acc[me][nt][r]);
                    }
        }
        LGKM0(); BAR();
        // OUT[:, e-half] = P * Hh^T + bb
        #pragma unroll
        for (int ec = 0; ec < 2; ++ec) {
            f32x4 acc[2][2];
            #pragma unroll
            for (int i = 0; i < 2; ++i)
                #pragma unroll
                for (int j = 0; j < 2; ++j) acc[i][j] = f32x4{0.f,0.f,0.f,0.f};
            #pragma unroll
            for (int ks = 0; ks < 4; ++ks) {
                short8 hb[2];
                #pragma unroll
                for (int nt = 0; nt < 2; ++nt) {
                    int erl = (nh*4 + ec*2 + nt)*16 + lr;
                    hb[nt] = *(const short8*)(lds + R_B + erl*256 + ((ks*64 + lg*16) ^ ((erl&7)<<4)));
                }
                PRIO1();
                #pragma unroll
                for (int mt = 0; mt < 2; ++mt)
                    #pragma unroll
                    for (int nt = 0; nt < 2; ++nt)
                        acc[mt][nt] = __builtin_amdgcn_mfma_f32_16x16x32_bf16(pa[mt][ks], hb[nt], acc[mt][nt], 0, 0, 0);
                PRIO0();
            }
            #pragma unroll
            for (int nt = 0; nt < 2; ++nt) {
                int e = eh*128 + (nh*4 + ec*2 + nt)*16 + lr;
                float bbv = bbp[e];
                #pragma unroll
                for (int mt = 0; mt < 2; ++mt)
                    #pragma unroll
                    for (int r = 0; r < 4; ++r) {
                        int t = mq*32 + mt*16 + lg*4 + r;
                        out[((size_t)bid * TT + t) * 256 + e] = acc[mt][nt][r] + bbv;
                    }
            }
        }
        if (eh == 0) { LGKM0(); BAR(); }   // protect R_B overwrite
    }
}

extern "C" void kernel_launch(void* const* d_in, const int* in_sizes, int n_in,
                              void* d_out, int out_size, void* d_ws, size_t ws_size,
                              hipStream_t stream) {
    (void)in_sizes; (void)n_in; (void)out_size; (void)ws_size; // needs ws_size >= 18948128
    const float* x  = (const float*)d_in[0];
    const float* Wq = (const float*)d_in[1];
    const float* bq = (const float*)d_in[2];
    const float* Wk = (const float*)d_in[3];
    const float* bk = (const float*)d_in[4];
    const float* Wv = (const float*)d_in[5];
    const float* bv = (const float*)d_in[6];
    const float* Wp = (const float*)d_in[7];
    const float* bp = (const float*)d_in[8];
    char* ws = (char*)d_ws;

    hipFuncSetAttribute((const void*)convert_pre,
                        hipFuncAttributeMaxDynamicSharedMemorySize, 65536);
    convert_pre<<<dim3(536), dim3(256), 65536, stream>>>(
        x, Wq, bq, Wk, bk, Wv, bv, Wp, bp, ws);

    hipFuncSetAttribute((const void*)mha_fused,
                        hipFuncAttributeMaxDynamicSharedMemorySize, LDS_SIZE);
    mha_fused<<<dim3(2048), dim3(512), LDS_SIZE, stream>>>(ws, (float*)d_out);
}

// Round 13
// 296.886 us; speedup vs baseline: 2.2723x; 1.0827x over previous
//
#include <hip/hip_runtime.h>
#include <hip/hip_bf16.h>
#include <stdint.h>

// Fused causal MHA, B=256,T=128,H=8,D=256,C=256. One block per (h,b).
// Round 13: round-12 structure, register-lean: X A-frags streamed from ws
// (no persistent xf, -32 regs), UV/RED overlaid into R_B -> LDS = 64KB.
// Target: demand <= ~120 regs so 16 waves (2 blocks) fit per CU.

#define TT 128

typedef __attribute__((ext_vector_type(8))) short short8;
typedef __attribute__((ext_vector_type(4))) float f32x4;

// ---- ws map (total 18948128 B < proven-available 20054016) ----
#define WS_X    0u                       // 256 b x 64KB  X A/B-frags
#define WS_M    16777216u                // 8 h x 128KB   M^T-layout B-frags (scaled 1/16)
#define WS_WM   17825792u                // 8 h x 128KB   WM A-frags
#define WS_WB   18874368u                // 8 h x 8KB     [w2;w1] B-frags (rows 0,1), zero-filled
#define WS_BB   18939904u                // 8 h x 1KB     bb fp32
#define WS_CQ   18948096u                // 8 x 4B        cqk fp32

// ---- LDS map (65536 B -> 2 blocks/CU) ----
#define R_A    0        // T1-half [128t][256B swz] -> P [128t][256B swz]
#define R_B    32768    // Ph2/3: H-half [128e][256B swz]; before that: UV/RED scratch
#define R_UV   32768    // v[128] f32 | u[128] f32   (dead once softmax done)
#define R_RED  33792    // redM[256] | redS[256]     (dead once softmax done)
#define LDS_SIZE 65536

#define LGKM0()  asm volatile("s_waitcnt lgkmcnt(0)" ::: "memory")
#define BAR()    do { asm volatile("" ::: "memory"); __builtin_amdgcn_s_barrier(); asm volatile("" ::: "memory"); } while (0)
#define PRIO1()  __builtin_amdgcn_s_setprio(1)
#define PRIO0()  __builtin_amdgcn_s_setprio(0)

__device__ __forceinline__ unsigned short f2bf(float x) {
    union { float f; unsigned u; } v; v.f = x;
    unsigned r = v.u + 0x7FFFu + ((v.u >> 16) & 1u);
    return (unsigned short)(r >> 16);
}
__device__ __forceinline__ unsigned pk2(float a, float b) {
    return (unsigned)f2bf(a) | ((unsigned)f2bf(b) << 16);
}

// =============== convert / fold kernel (unchanged from round 9) ============
__global__ __launch_bounds__(256) void convert_pre(
    const float* __restrict__ x,
    const float* __restrict__ Wq, const float* __restrict__ bq,
    const float* __restrict__ Wk, const float* __restrict__ bk,
    const float* __restrict__ Wv, const float* __restrict__ bv,
    const float* __restrict__ Wp, const float* __restrict__ bp,
    char* __restrict__ ws)
{
    extern __shared__ char clds[];
    const int tid = threadIdx.x;
    const int bid = blockIdx.x;

    if (bid < 256) {
        const float* src = x + (size_t)bid * 32768;
        char* dst = ws + WS_X + (size_t)bid * 65536;
        for (int i = tid; i < 8192; i += 256) {
            float4 v = ((const float4*)src)[i];
            int row = i >> 6, c4 = i & 63;
            uint2 u; u.x = pk2(v.x, v.y); u.y = pk2(v.z, v.w);
            *(uint2*)(clds + row * 512 + ((c4 * 8) ^ ((row & 7) << 4))) = u;
        }
        __syncthreads();
        for (int i = tid; i < 4096; i += 256) {
            int l = i & 63, ks = (i >> 6) & 7, g = i >> 9;
            int r = g * 16 + (l & 15);
            int boff = ks * 64 + (l >> 4) * 16;
            uint4 q = *(const uint4*)(clds + r * 512 + (boff ^ ((r & 7) << 4)));
            ((uint4*)dst)[i] = q;
        }
        return;
    }
    if (bid < 384) {
        int id = bid - 256, h = id >> 4, st = id & 15;
        float* wkL = (float*)clds;
        for (int i = tid; i < 4096; i += 256) {
            int d = i >> 4, cc = i & 15;
            wkL[i] = Wk[(size_t)h * 65536 + d * 256 + st * 16 + cc];
        }
        __syncthreads();
        const int c = tid;
        float acc[16];
        #pragma unroll
        for (int j = 0; j < 16; ++j) acc[j] = 0.f;
        #pragma unroll 4
        for (int d = 0; d < 256; ++d) {
            float a = Wq[(size_t)h * 65536 + d * 256 + c];
            #pragma unroll
            for (int j = 0; j < 16; ++j) acc[j] += a * wkL[d * 16 + j];
        }
        char* base = ws + WS_M + (size_t)h * 131072;
        int ks = c >> 5, lgp = (c >> 3) & 3, jb = c & 7;
        #pragma unroll
        for (int j = 0; j < 16; ++j) {
            int cp = st * 16 + j;
            *(unsigned short*)(base + (((st * 8 + ks)) << 10)
                + ((cp & 15) + 16 * lgp) * 16 + jb * 2) = f2bf(acc[j] * 0.0625f);
        }
        return;
    }
    if (bid < 512) {
        int id = bid - 384, h = id >> 4, st = id & 15;
        float* wpL = (float*)clds;
        for (int i = tid; i < 4096; i += 256) {
            int e = i >> 8, d = i & 255;
            wpL[e * 257 + d] = Wp[(size_t)(st * 16 + e) * 256 + d];
        }
        __syncthreads();
        const int c = tid;
        float acc[16];
        #pragma unroll
        for (int j = 0; j < 16; ++j) acc[j] = 0.f;
        #pragma unroll 4
        for (int d = 0; d < 256; ++d) {
            float wv = Wv[(size_t)h * 65536 + d * 256 + c];
            #pragma unroll
            for (int j = 0; j < 16; ++j) acc[j] += wv * wpL[j * 257 + d];
        }
        char* base = ws + WS_WM + (size_t)h * 131072;
        int ks = c >> 5, lgp = (c >> 3) & 3, jb = c & 7;
        #pragma unroll
        for (int j = 0; j < 16; ++j) {
            *(unsigned short*)(base + (((st * 8 + ks)) << 10)
                + (j + 16 * lgp) * 16 + jb * 2) = f2bf(acc[j]);
        }
        return;
    }
    if (bid < 520) {
        const int h = bid - 512;
        {
            uint4 z = {0u,0u,0u,0u};
            for (int i = tid; i < 512; i += 256)
                ((uint4*)(ws + WS_WB + (size_t)h * 8192))[i] = z;
        }
        float* tK = (float*)clds;
        float* tQ = (float*)(clds + 16384);
        const int c = tid;
        float s1 = 0.f, s2 = 0.f;
        for (int d0 = 0; d0 < 256; d0 += 16) {
            __syncthreads();
            for (int i = tid; i < 1024; i += 256) {
                int row = i >> 6, c4 = i & 63;
                ((float4*)tK)[row * 64 + c4] =
                    ((const float4*)(Wk + (size_t)h * 65536 + (size_t)(d0 + row) * 256))[c4];
                ((float4*)tQ)[row * 64 + c4] =
                    ((const float4*)(Wq + (size_t)h * 65536 + (size_t)(d0 + row) * 256))[c4];
            }
            __syncthreads();
            #pragma unroll
            for (int dd = 0; dd < 16; ++dd) {
                s1 += tK[dd * 256 + c] * bq[h * 256 + d0 + dd];
                s2 += tQ[dd * 256 + c] * bk[h * 256 + d0 + dd];
            }
        }
        int ks = c >> 5, lgp = (c >> 3) & 3, jb = c & 7;
        char* base = ws + WS_WB + (size_t)h * 8192 + ks * 1024;
        *(unsigned short*)(base + (0 + 16 * lgp) * 16 + jb * 2) = f2bf(s2 * 0.0625f);
        *(unsigned short*)(base + (1 + 16 * lgp) * 16 + jb * 2) = f2bf(s1 * 0.0625f);
        float* red = (float*)(clds + 32768);
        red[tid] = bq[h * 256 + tid] * bk[h * 256 + tid];
        __syncthreads();
        if (tid == 0) {
            float cq = 0.f;
            for (int d = 0; d < 256; ++d) cq += red[d];
            *(float*)(ws + WS_CQ + h * 4) = cq * 0.0625f;
        }
        return;
    }
    {
        const int st = bid - 520;
        float* wpT = (float*)clds;
        float* bvL = (float*)(clds + 17408);
        for (int i = tid; i < 1024; i += 256) {
            int row = i >> 6, c4 = i & 63;
            float4 v = ((const float4*)(Wp + (size_t)(st * 16 + row) * 256))[c4];
            float* dstp = wpT + row * 257 + c4 * 4;
            dstp[0] = v.x; dstp[1] = v.y; dstp[2] = v.z; dstp[3] = v.w;
        }
        for (int i = tid; i < 512; i += 256)
            ((float4*)bvL)[i] = ((const float4*)bv)[i];
        __syncthreads();
        const int el = tid >> 4, dg = tid & 15;
        #pragma unroll
        for (int h = 0; h < 8; ++h) {
            float p = 0.f;
            #pragma unroll
            for (int dd = 0; dd < 16; ++dd) {
                int d = dg * 16 + dd;
                p += bvL[h * 256 + d] * wpT[el * 257 + d];
            }
            p += __shfl_xor(p, 1);
            p += __shfl_xor(p, 2);
            p += __shfl_xor(p, 4);
            p += __shfl_xor(p, 8);
            if (dg == 0)
                *(float*)(ws + WS_BB + (size_t)h * 1024 + (st * 16 + el) * 4)
                    = bp[st * 16 + el] + p;
        }
        return;
    }
}

// =============== main fused kernel =========================================
__global__ __launch_bounds__(512, 2) void mha_fused(
    const char* __restrict__ ws, float* __restrict__ out)
{
    extern __shared__ char lds[];
    const int tid = threadIdx.x;
    const int w  = tid >> 6, l = tid & 63;
    const int lg = l >> 4, lr = l & 15;
    const int mq = w & 3, nh = w >> 2;      // 4 M-waves x 2 N-waves
    const int bid = blockIdx.x;
    const int h = bid >> 8, b = bid & 255;

    const char* Xf  = ws + WS_X  + (size_t)b * 65536;
    const char* Mh  = ws + WS_M  + (size_t)h * 131072;
    const char* WMh = ws + WS_WM + (size_t)h * 131072;
    const char* WBh = ws + WS_WB + (size_t)h * 8192;

    // ---- Ph0a: [v|u] = X * [w2;w1]^T  (X frags streamed) ----
    {
        f32x4 vacc[2] = {f32x4{0.f,0.f,0.f,0.f}, f32x4{0.f,0.f,0.f,0.f}};
        #pragma unroll
        for (int ks = 0; ks < 8; ++ks) {
            short8 wb  = *(const short8*)(WBh + (ks << 10) + l*16);
            short8 xa0 = *(const short8*)(Xf + (((mq*2 + 0)*8 + ks) << 10) + l*16);
            short8 xa1 = *(const short8*)(Xf + (((mq*2 + 1)*8 + ks) << 10) + l*16);
            vacc[0] = __builtin_amdgcn_mfma_f32_16x16x32_bf16(xa0, wb, vacc[0], 0, 0, 0);
            vacc[1] = __builtin_amdgcn_mfma_f32_16x16x32_bf16(xa1, wb, vacc[1], 0, 0, 0);
        }
        if (nh == 0 && lr < 2) {
            #pragma unroll
            for (int mt = 0; mt < 2; ++mt)
                #pragma unroll
                for (int r = 0; r < 4; ++r) {
                    int t = mq*32 + mt*16 + lg*4 + r;
                    *(float*)(lds + R_UV + lr*512 + t*4) = vacc[mt][r];
                }
        }
    }

    // ---- Ph0b/Ph1: T1 halves (128 cols) -> S accumulation ----
    f32x4 sacc[2][4];
    #pragma unroll
    for (int i = 0; i < 2; ++i)
        #pragma unroll
        for (int j = 0; j < 4; ++j) sacc[i][j] = f32x4{0.f,0.f,0.f,0.f};

    #pragma unroll
    for (int h2 = 0; h2 < 2; ++h2) {
        // T1h = X * N[:, half] -> R_A  [128t][256B swz]
        const int ga = h2*8 + nh*4;
        f32x4 acc[2][4];
        #pragma unroll
        for (int i = 0; i < 2; ++i)
            #pragma unroll
            for (int j = 0; j < 4; ++j) acc[i][j] = f32x4{0.f,0.f,0.f,0.f};
        #pragma unroll
        for (int ks = 0; ks < 8; ++ks) {
            short8 xa[2];
            #pragma unroll
            for (int mt = 0; mt < 2; ++mt)
                xa[mt] = *(const short8*)(Xf + (((mq*2 + mt)*8 + ks) << 10) + l*16);
            short8 nb[4];
            #pragma unroll
            for (int nt = 0; nt < 4; ++nt)
                nb[nt] = *(const short8*)(Mh + (((ga+nt)*8 + ks) << 10) + l*16);
            PRIO1();
            #pragma unroll
            for (int mt = 0; mt < 2; ++mt)
                #pragma unroll
                for (int nt = 0; nt < 4; ++nt)
                    acc[mt][nt] = __builtin_amdgcn_mfma_f32_16x16x32_bf16(xa[mt], nb[nt], acc[mt][nt], 0, 0, 0);
            PRIO0();
        }
        #pragma unroll
        for (int mt = 0; mt < 2; ++mt)
            #pragma unroll
            for (int nt = 0; nt < 4; ++nt)
                #pragma unroll
                for (int r = 0; r < 4; ++r) {
                    int t = mq*32 + mt*16 + lg*4 + r;
                    int cpl = (nh*4+nt)*16 + lr;     // col within half
                    *(unsigned short*)(lds + R_A + t*256 + ((cpl*2) ^ ((t&7)<<4)))
                        = f2bf(acc[mt][nt][r]);
                }
        LGKM0(); BAR();
        // S += T1h * X[:, half]^T
        #pragma unroll
        for (int ks2 = 0; ks2 < 4; ++ks2) {
            short8 ta[2];
            #pragma unroll
            for (int mt = 0; mt < 2; ++mt) {
                int t2 = mq*32 + mt*16 + lr;
                ta[mt] = *(const short8*)(lds + R_A + t2*256 + ((ks2*64 + lg*16) ^ ((t2&7)<<4)));
            }
            short8 sb[4];
            #pragma unroll
            for (int nt = 0; nt < 4; ++nt)
                sb[nt] = *(const short8*)(Xf + (((nh*4+nt)*8 + (h2*4+ks2)) << 10) + l*16);
            PRIO1();
            #pragma unroll
            for (int mt = 0; mt < 2; ++mt)
                #pragma unroll
                for (int nt = 0; nt < 4; ++nt)
                    sacc[mt][nt] = __builtin_amdgcn_mfma_f32_16x16x32_bf16(ta[mt], sb[nt], sacc[mt][nt], 0, 0, 0);
            PRIO0();
        }
        if (h2 == 0) { LGKM0(); BAR(); }   // protect R_A overwrite
    }

    // ---- softmax: bias add, mask, max, exp, sum, P -> R_A ----
    {
        const float cq = *(const float*)(ws + WS_CQ + h*4);
        float uu[4];
        #pragma unroll
        for (int nt = 0; nt < 4; ++nt)
            uu[nt] = *(const float*)(lds + R_UV + 512 + (nh*64 + nt*16 + lr)*4);
        float* redM = (float*)(lds + R_RED);
        float* redS = redM + 256;
        float rmax[2][4];
        #pragma unroll
        for (int mt = 0; mt < 2; ++mt)
            #pragma unroll
            for (int r = 0; r < 4; ++r) {
                int t = mq*32 + mt*16 + lg*4 + r;
                float vt = *(const float*)(lds + R_UV + t*4) + cq;
                float m = -1e30f;
                #pragma unroll
                for (int nt = 0; nt < 4; ++nt) {
                    int s = nh*64 + nt*16 + lr;
                    float sv = sacc[mt][nt][r] + vt + uu[nt];
                    if (s > t) sv = -1e30f;
                    sacc[mt][nt][r] = sv;
                    m = fmaxf(m, sv);
                }
                m = fmaxf(m, __shfl_xor(m, 1));
                m = fmaxf(m, __shfl_xor(m, 2));
                m = fmaxf(m, __shfl_xor(m, 4));
                m = fmaxf(m, __shfl_xor(m, 8));
                rmax[mt][r] = m;
            }
        if (lr == 0) {
            #pragma unroll
            for (int mt = 0; mt < 2; ++mt)
                #pragma unroll
                for (int r = 0; r < 4; ++r)
                    redM[nh*128 + mq*32 + mt*16 + lg*4 + r] = rmax[mt][r];
        }
        LGKM0(); BAR();
        float rsum[2][4];
        #pragma unroll
        for (int mt = 0; mt < 2; ++mt)
            #pragma unroll
            for (int r = 0; r < 4; ++r) {
                int t = mq*32 + mt*16 + lg*4 + r;
                float m = fmaxf(redM[t], redM[128 + t]);
                float ssum = 0.f;
                #pragma unroll
                for (int nt = 0; nt < 4; ++nt) {
                    float p = __expf(sacc[mt][nt][r] - m);
                    sacc[mt][nt][r] = p;
                    ssum += p;
                }
                ssum += __shfl_xor(ssum, 1);
                ssum += __shfl_xor(ssum, 2);
                ssum += __shfl_xor(ssum, 4);
                ssum += __shfl_xor(ssum, 8);
                rsum[mt][r] = ssum;
            }
        if (lr == 0) {
            #pragma unroll
            for (int mt = 0; mt < 2; ++mt)
                #pragma unroll
                for (int r = 0; r < 4; ++r)
                    redS[nh*128 + mq*32 + mt*16 + lg*4 + r] = rsum[mt][r];
        }
        LGKM0(); BAR();
        #pragma unroll
        for (int mt = 0; mt < 2; ++mt)
            #pragma unroll
            for (int r = 0; r < 4; ++r) {
                int t = mq*32 + mt*16 + lg*4 + r;
                float inv = 1.0f / (redS[t] + redS[128 + t]);
                #pragma unroll
                for (int nt = 0; nt < 4; ++nt) {
                    int s = nh*64 + nt*16 + lr;
                    *(unsigned short*)(lds + R_A + t*256 + ((s*2) ^ ((t&7)<<4)))
                        = f2bf(sacc[mt][nt][r] * inv);
                }
            }
    }
    LGKM0(); BAR();

    // P A-frags (live through both e-halves)
    short8 pa[2][4];
    #pragma unroll
    for (int mt = 0; mt < 2; ++mt) {
        int t2 = mq*32 + mt*16 + lr;
        #pragma unroll
        for (int ks = 0; ks < 4; ++ks)
            pa[mt][ks] = *(const short8*)(lds + R_A + t2*256 + ((ks*64 + lg*16) ^ ((t2&7)<<4)));
    }

    // ---- Ph2/Ph3: H halves (128 rows) -> OUT e-halves ----
    const float* bbp = (const float*)(ws + WS_BB + h*1024);
    #pragma unroll
    for (int eh = 0; eh < 2; ++eh) {
        // Hh = WM[eh half rows] * X^T -> R_B [128e local][128s], swz
        {
            f32x4 acc[2][4];
            #pragma unroll
            for (int i = 0; i < 2; ++i)
                #pragma unroll
                for (int j = 0; j < 4; ++j) acc[i][j] = f32x4{0.f,0.f,0.f,0.f};
            #pragma unroll
            for (int ks = 0; ks < 8; ++ks) {
                short8 wa[2];
                #pragma unroll
                for (int me = 0; me < 2; ++me)
                    wa[me] = *(const short8*)(WMh + (((eh*8 + mq*2+me)*8 + ks) << 10) + l*16);
                short8 sb[4];
                #pragma unroll
                for (int nt = 0; nt < 4; ++nt)
                    sb[nt] = *(const short8*)(Xf + (((nh*4 + nt)*8 + ks) << 10) + l*16);
                PRIO1();
                #pragma unroll
                for (int me = 0; me < 2; ++me)
                    #pragma unroll
                    for (int nt = 0; nt < 4; ++nt)
                        acc[me][nt] = __builtin_amdgcn_mfma_f32_16x16x32_bf16(wa[me], sb[nt], acc[me][nt], 0, 0, 0);
                PRIO0();
            }
            #pragma unroll
            for (int me = 0; me < 2; ++me)
                #pragma unroll
                for (int nt = 0; nt < 4; ++nt)
                    #pragma unroll
                    for (int r = 0; r < 4; ++r) {
                        int el = (mq*2+me)*16 + lg*4 + r;
                        int s  = (nh*4 + nt)*16 + lr;
                        *(unsigned short*)(lds + R_B + el*256 + ((s*2) ^ ((el&7)<<4)))
                            = f2bf(acc[me][nt][r]);
                    }
        }
        LGKM0(); BAR();
        // OUT[:, e-half] = P * Hh^T + bb
        #pragma unroll
        for (int ec = 0; ec < 2; ++ec) {
            f32x4 acc[2][2];
            #pragma unroll
            for (int i = 0; i < 2; ++i)
                #pragma unroll
                for (int j = 0; j < 2; ++j) acc[i][j] = f32x4{0.f,0.f,0.f,0.f};
            #pragma unroll
            for (int ks = 0; ks < 4; ++ks) {
                short8 hb[2];
                #pragma unroll
                for (int nt = 0; nt < 2; ++nt) {
                    int erl = (nh*4 + ec*2 + nt)*16 + lr;
                    hb[nt] = *(const short8*)(lds + R_B + erl*256 + ((ks*64 + lg*16) ^ ((erl&7)<<4)));
                }
                PRIO1();
                #pragma unroll
                for (int mt = 0; mt < 2; ++mt)
                    #pragma unroll
                    for (int nt = 0; nt < 2; ++nt)
                        acc[mt][nt] = __builtin_amdgcn_mfma_f32_16x16x32_bf16(pa[mt][ks], hb[nt], acc[mt][nt], 0, 0, 0);
                PRIO0();
            }
            #pragma unroll
            for (int nt = 0; nt < 2; ++nt) {
                int e = eh*128 + (nh*4 + ec*2 + nt)*16 + lr;
                float bbv = bbp[e];
                #pragma unroll
                for (int mt = 0; mt < 2; ++mt)
                    #pragma unroll
                    for (int r = 0; r < 4; ++r) {
                        int t = mq*32 + mt*16 + lg*4 + r;
                        out[((size_t)bid * TT + t) * 256 + e] = acc[mt][nt][r] + bbv;
                    }
            }
        }
        if (eh == 0) { LGKM0(); BAR(); }   // protect R_B overwrite
    }
}

extern "C" void kernel_launch(void* const* d_in, const int* in_sizes, int n_in,
                              void* d_out, int out_size, void* d_ws, size_t ws_size,
                              hipStream_t stream) {
    (void)in_sizes; (void)n_in; (void)out_size; (void)ws_size; // needs ws_size >= 18948128
    const float* x  = (const float*)d_in[0];
    const float* Wq = (const float*)d_in[1];
    const float* bq = (const float*)d_in[2];
    const float* Wk = (const float*)d_in[3];
    const float* bk = (const float*)d_in[4];
    const float* Wv = (const float*)d_in[5];
    const float* bv = (const float*)d_in[6];
    const float* Wp = (const float*)d_in[7];
    const float* bp = (const float*)d_in[8];
    char* ws = (char*)d_ws;

    hipFuncSetAttribute((const void*)convert_pre,
                        hipFuncAttributeMaxDynamicSharedMemorySize, 65536);
    convert_pre<<<dim3(536), dim3(256), 65536, stream>>>(
        x, Wq, bq, Wk, bk, Wv, bv, Wp, bp, ws);

    hipFuncSetAttribute((const void*)mha_fused,
                        hipFuncAttributeMaxDynamicSharedMemorySize, LDS_SIZE);
    mha_fused<<<dim3(2048), dim3(512), LDS_SIZE, stream>>>(ws, (float*)d_out);
}

// Round 14
// 279.149 us; speedup vs baseline: 2.4167x; 1.0635x over previous
//
#include <hip/hip_runtime.h>
#include <hip/hip_bf16.h>
#include <stdint.h>

// Fused causal MHA, B=256,T=128,H=8,D=256,C=256. One block per (h,b).
// Round 14: accept 1 block/CU. (a) XCD-aware (h,b) mapping so the 8 h-blocks
// of one b run on one XCD (X L2-hot); (b) full-width 64KB T1 buffer -> merged
// T1/S phases, 7 barriers; (c) launch_bounds(512,1) lifts reg cap (no spill).

#define TT 128

typedef __attribute__((ext_vector_type(8))) short short8;
typedef __attribute__((ext_vector_type(4))) float f32x4;

// ---- ws map (total 18948128 B < proven-available 20054016) ----
#define WS_X    0u                       // 256 b x 64KB  X A/B-frags
#define WS_M    16777216u                // 8 h x 128KB   M^T-layout B-frags (scaled 1/16)
#define WS_WM   17825792u                // 8 h x 128KB   WM A-frags
#define WS_WB   18874368u                // 8 h x 8KB     [w2;w1] B-frags (rows 0,1), zero-filled
#define WS_BB   18939904u                // 8 h x 1KB     bb fp32
#define WS_CQ   18948096u                // 8 x 4B        cqk fp32

// ---- LDS map (68608 B) ----
#define R_A    0        // T1 full [128t][512B swz] spans R_A+R_B; P [128t][256B swz] later in R_A
#define R_B    32768    // H-half [128e][256B swz] in Ph2/3
#define R_UV   65536    // v[128] f32 | u[128] f32
#define R_RED  66560    // redM[256] | redS[256]
#define LDS_SIZE 68608

#define LGKM0()  asm volatile("s_waitcnt lgkmcnt(0)" ::: "memory")
#define BAR()    do { asm volatile("" ::: "memory"); __builtin_amdgcn_s_barrier(); asm volatile("" ::: "memory"); } while (0)
#define PRIO1()  __builtin_amdgcn_s_setprio(1)
#define PRIO0()  __builtin_amdgcn_s_setprio(0)

__device__ __forceinline__ unsigned short f2bf(float x) {
    union { float f; unsigned u; } v; v.f = x;
    unsigned r = v.u + 0x7FFFu + ((v.u >> 16) & 1u);
    return (unsigned short)(r >> 16);
}
__device__ __forceinline__ unsigned pk2(float a, float b) {
    return (unsigned)f2bf(a) | ((unsigned)f2bf(b) << 16);
}

// =============== convert / fold kernel (unchanged from round 9) ============
__global__ __launch_bounds__(256) void convert_pre(
    const float* __restrict__ x,
    const float* __restrict__ Wq, const float* __restrict__ bq,
    const float* __restrict__ Wk, const float* __restrict__ bk,
    const float* __restrict__ Wv, const float* __restrict__ bv,
    const float* __restrict__ Wp, const float* __restrict__ bp,
    char* __restrict__ ws)
{
    extern __shared__ char clds[];
    const int tid = threadIdx.x;
    const int bid = blockIdx.x;

    if (bid < 256) {
        const float* src = x + (size_t)bid * 32768;
        char* dst = ws + WS_X + (size_t)bid * 65536;
        for (int i = tid; i < 8192; i += 256) {
            float4 v = ((const float4*)src)[i];
            int row = i >> 6, c4 = i & 63;
            uint2 u; u.x = pk2(v.x, v.y); u.y = pk2(v.z, v.w);
            *(uint2*)(clds + row * 512 + ((c4 * 8) ^ ((row & 7) << 4))) = u;
        }
        __syncthreads();
        for (int i = tid; i < 4096; i += 256) {
            int l = i & 63, ks = (i >> 6) & 7, g = i >> 9;
            int r = g * 16 + (l & 15);
            int boff = ks * 64 + (l >> 4) * 16;
            uint4 q = *(const uint4*)(clds + r * 512 + (boff ^ ((r & 7) << 4)));
            ((uint4*)dst)[i] = q;
        }
        return;
    }
    if (bid < 384) {
        int id = bid - 256, h = id >> 4, st = id & 15;
        float* wkL = (float*)clds;
        for (int i = tid; i < 4096; i += 256) {
            int d = i >> 4, cc = i & 15;
            wkL[i] = Wk[(size_t)h * 65536 + d * 256 + st * 16 + cc];
        }
        __syncthreads();
        const int c = tid;
        float acc[16];
        #pragma unroll
        for (int j = 0; j < 16; ++j) acc[j] = 0.f;
        #pragma unroll 4
        for (int d = 0; d < 256; ++d) {
            float a = Wq[(size_t)h * 65536 + d * 256 + c];
            #pragma unroll
            for (int j = 0; j < 16; ++j) acc[j] += a * wkL[d * 16 + j];
        }
        char* base = ws + WS_M + (size_t)h * 131072;
        int ks = c >> 5, lgp = (c >> 3) & 3, jb = c & 7;
        #pragma unroll
        for (int j = 0; j < 16; ++j) {
            int cp = st * 16 + j;
            *(unsigned short*)(base + (((st * 8 + ks)) << 10)
                + ((cp & 15) + 16 * lgp) * 16 + jb * 2) = f2bf(acc[j] * 0.0625f);
        }
        return;
    }
    if (bid < 512) {
        int id = bid - 384, h = id >> 4, st = id & 15;
        float* wpL = (float*)clds;
        for (int i = tid; i < 4096; i += 256) {
            int e = i >> 8, d = i & 255;
            wpL[e * 257 + d] = Wp[(size_t)(st * 16 + e) * 256 + d];
        }
        __syncthreads();
        const int c = tid;
        float acc[16];
        #pragma unroll
        for (int j = 0; j < 16; ++j) acc[j] = 0.f;
        #pragma unroll 4
        for (int d = 0; d < 256; ++d) {
            float wv = Wv[(size_t)h * 65536 + d * 256 + c];
            #pragma unroll
            for (int j = 0; j < 16; ++j) acc[j] += wv * wpL[j * 257 + d];
        }
        char* base = ws + WS_WM + (size_t)h * 131072;
        int ks = c >> 5, lgp = (c >> 3) & 3, jb = c & 7;
        #pragma unroll
        for (int j = 0; j < 16; ++j) {
            *(unsigned short*)(base + (((st * 8 + ks)) << 10)
                + (j + 16 * lgp) * 16 + jb * 2) = f2bf(acc[j]);
        }
        return;
    }
    if (bid < 520) {
        const int h = bid - 512;
        {
            uint4 z = {0u,0u,0u,0u};
            for (int i = tid; i < 512; i += 256)
                ((uint4*)(ws + WS_WB + (size_t)h * 8192))[i] = z;
        }
        float* tK = (float*)clds;
        float* tQ = (float*)(clds + 16384);
        const int c = tid;
        float s1 = 0.f, s2 = 0.f;
        for (int d0 = 0; d0 < 256; d0 += 16) {
            __syncthreads();
            for (int i = tid; i < 1024; i += 256) {
                int row = i >> 6, c4 = i & 63;
                ((float4*)tK)[row * 64 + c4] =
                    ((const float4*)(Wk + (size_t)h * 65536 + (size_t)(d0 + row) * 256))[c4];
                ((float4*)tQ)[row * 64 + c4] =
                    ((const float4*)(Wq + (size_t)h * 65536 + (size_t)(d0 + row) * 256))[c4];
            }
            __syncthreads();
            #pragma unroll
            for (int dd = 0; dd < 16; ++dd) {
                s1 += tK[dd * 256 + c] * bq[h * 256 + d0 + dd];
                s2 += tQ[dd * 256 + c] * bk[h * 256 + d0 + dd];
            }
        }
        int ks = c >> 5, lgp = (c >> 3) & 3, jb = c & 7;
        char* base = ws + WS_WB + (size_t)h * 8192 + ks * 1024;
        *(unsigned short*)(base + (0 + 16 * lgp) * 16 + jb * 2) = f2bf(s2 * 0.0625f);
        *(unsigned short*)(base + (1 + 16 * lgp) * 16 + jb * 2) = f2bf(s1 * 0.0625f);
        float* red = (float*)(clds + 32768);
        red[tid] = bq[h * 256 + tid] * bk[h * 256 + tid];
        __syncthreads();
        if (tid == 0) {
            float cq = 0.f;
            for (int d = 0; d < 256; ++d) cq += red[d];
            *(float*)(ws + WS_CQ + h * 4) = cq * 0.0625f;
        }
        return;
    }
    {
        const int st = bid - 520;
        float* wpT = (float*)clds;
        float* bvL = (float*)(clds + 17408);
        for (int i = tid; i < 1024; i += 256) {
            int row = i >> 6, c4 = i & 63;
            float4 v = ((const float4*)(Wp + (size_t)(st * 16 + row) * 256))[c4];
            float* dstp = wpT + row * 257 + c4 * 4;
            dstp[0] = v.x; dstp[1] = v.y; dstp[2] = v.z; dstp[3] = v.w;
        }
        for (int i = tid; i < 512; i += 256)
            ((float4*)bvL)[i] = ((const float4*)bv)[i];
        __syncthreads();
        const int el = tid >> 4, dg = tid & 15;
        #pragma unroll
        for (int h = 0; h < 8; ++h) {
            float p = 0.f;
            #pragma unroll
            for (int dd = 0; dd < 16; ++dd) {
                int d = dg * 16 + dd;
                p += bvL[h * 256 + d] * wpT[el * 257 + d];
            }
            p += __shfl_xor(p, 1);
            p += __shfl_xor(p, 2);
            p += __shfl_xor(p, 4);
            p += __shfl_xor(p, 8);
            if (dg == 0)
                *(float*)(ws + WS_BB + (size_t)h * 1024 + (st * 16 + el) * 4)
                    = bp[st * 16 + el] + p;
        }
        return;
    }
}

// =============== main fused kernel =========================================
__global__ __launch_bounds__(512, 1) void mha_fused(
    const char* __restrict__ ws, float* __restrict__ out)
{
    extern __shared__ char lds[];
    const int tid = threadIdx.x;
    const int w  = tid >> 6, l = tid & 63;
    const int lg = l >> 4, lr = l & 15;
    const int mq = w & 3, nh = w >> 2;      // 4 M-waves x 2 N-waves
    // XCD-aware mapping: all 8 h-blocks of one b on the SAME XCD (bid%8)
    const int bid = blockIdx.x;
    const int xcd = bid & 7, j = bid >> 3;
    const int h = j & 7;
    const int b = ((j >> 3) << 3) | xcd;
    const size_t orow = ((size_t)(h * 256 + b)) * TT;   // output row base

    const char* Xf  = ws + WS_X  + (size_t)b * 65536;
    const char* Mh  = ws + WS_M  + (size_t)h * 131072;
    const char* WMh = ws + WS_WM + (size_t)h * 131072;
    const char* WBh = ws + WS_WB + (size_t)h * 8192;

    // ---- Ph0a: [v|u] = X * [w2;w1]^T  (X frags streamed) ----
    {
        f32x4 vacc[2] = {f32x4{0.f,0.f,0.f,0.f}, f32x4{0.f,0.f,0.f,0.f}};
        #pragma unroll
        for (int ks = 0; ks < 8; ++ks) {
            short8 wb  = *(const short8*)(WBh + (ks << 10) + l*16);
            short8 xa0 = *(const short8*)(Xf + (((mq*2 + 0)*8 + ks) << 10) + l*16);
            short8 xa1 = *(const short8*)(Xf + (((mq*2 + 1)*8 + ks) << 10) + l*16);
            vacc[0] = __builtin_amdgcn_mfma_f32_16x16x32_bf16(xa0, wb, vacc[0], 0, 0, 0);
            vacc[1] = __builtin_amdgcn_mfma_f32_16x16x32_bf16(xa1, wb, vacc[1], 0, 0, 0);
        }
        if (nh == 0 && lr < 2) {
            #pragma unroll
            for (int mt = 0; mt < 2; ++mt)
                #pragma unroll
                for (int r = 0; r < 4; ++r) {
                    int t = mq*32 + mt*16 + lg*4 + r;
                    *(float*)(lds + R_UV + lr*512 + t*4) = vacc[mt][r];
                }
        }
    }

    // ---- Ph0b: T1 full = X * N -> lds[0,64K) [128t][512B swz], 2 col passes ----
    #pragma unroll
    for (int p2 = 0; p2 < 2; ++p2) {
        const int ga = p2*8 + nh*4;
        f32x4 acc[2][4];
        #pragma unroll
        for (int i = 0; i < 2; ++i)
            #pragma unroll
            for (int jj = 0; jj < 4; ++jj) acc[i][jj] = f32x4{0.f,0.f,0.f,0.f};
        #pragma unroll
        for (int ks = 0; ks < 8; ++ks) {
            short8 xa[2];
            #pragma unroll
            for (int mt = 0; mt < 2; ++mt)
                xa[mt] = *(const short8*)(Xf + (((mq*2 + mt)*8 + ks) << 10) + l*16);
            short8 nb[4];
            #pragma unroll
            for (int nt = 0; nt < 4; ++nt)
                nb[nt] = *(const short8*)(Mh + (((ga+nt)*8 + ks) << 10) + l*16);
            PRIO1();
            #pragma unroll
            for (int mt = 0; mt < 2; ++mt)
                #pragma unroll
                for (int nt = 0; nt < 4; ++nt)
                    acc[mt][nt] = __builtin_amdgcn_mfma_f32_16x16x32_bf16(xa[mt], nb[nt], acc[mt][nt], 0, 0, 0);
            PRIO0();
        }
        #pragma unroll
        for (int mt = 0; mt < 2; ++mt)
            #pragma unroll
            for (int nt = 0; nt < 4; ++nt)
                #pragma unroll
                for (int r = 0; r < 4; ++r) {
                    int t = mq*32 + mt*16 + lg*4 + r;
                    int cp = (ga+nt)*16 + lr;            // col 0..255
                    *(unsigned short*)(lds + R_A + t*512 + ((cp*2) ^ ((t&7)<<4)))
                        = f2bf(acc[mt][nt][r]);
                }
    }
    LGKM0(); BAR();

    // ---- Ph1: S = T1 * X^T (full K=256, one phase) ----
    f32x4 sacc[2][4];
    #pragma unroll
    for (int i = 0; i < 2; ++i)
        #pragma unroll
        for (int jj = 0; jj < 4; ++jj) sacc[i][jj] = f32x4{0.f,0.f,0.f,0.f};
    #pragma unroll
    for (int ks2 = 0; ks2 < 8; ++ks2) {
        short8 ta[2];
        #pragma unroll
        for (int mt = 0; mt < 2; ++mt) {
            int t2 = mq*32 + mt*16 + lr;
            ta[mt] = *(const short8*)(lds + R_A + t2*512 + ((ks2*64 + lg*16) ^ ((t2&7)<<4)));
        }
        short8 sb[4];
        #pragma unroll
        for (int nt = 0; nt < 4; ++nt)
            sb[nt] = *(const short8*)(Xf + (((nh*4+nt)*8 + ks2) << 10) + l*16);
        PRIO1();
        #pragma unroll
        for (int mt = 0; mt < 2; ++mt)
            #pragma unroll
            for (int nt = 0; nt < 4; ++nt)
                sacc[mt][nt] = __builtin_amdgcn_mfma_f32_16x16x32_bf16(ta[mt], sb[nt], sacc[mt][nt], 0, 0, 0);
        PRIO0();
    }

    // ---- softmax: bias add, mask, max, exp, sum, P -> R_A ----
    {
        const float cq = *(const float*)(ws + WS_CQ + h*4);
        float uu[4];
        #pragma unroll
        for (int nt = 0; nt < 4; ++nt)
            uu[nt] = *(const float*)(lds + R_UV + 512 + (nh*64 + nt*16 + lr)*4);
        float* redM = (float*)(lds + R_RED);
        float* redS = redM + 256;
        float rmax[2][4];
        #pragma unroll
        for (int mt = 0; mt < 2; ++mt)
            #pragma unroll
            for (int r = 0; r < 4; ++r) {
                int t = mq*32 + mt*16 + lg*4 + r;
                float vt = *(const float*)(lds + R_UV + t*4) + cq;
                float m = -1e30f;
                #pragma unroll
                for (int nt = 0; nt < 4; ++nt) {
                    int s = nh*64 + nt*16 + lr;
                    float sv = sacc[mt][nt][r] + vt + uu[nt];
                    if (s > t) sv = -1e30f;
                    sacc[mt][nt][r] = sv;
                    m = fmaxf(m, sv);
                }
                m = fmaxf(m, __shfl_xor(m, 1));
                m = fmaxf(m, __shfl_xor(m, 2));
                m = fmaxf(m, __shfl_xor(m, 4));
                m = fmaxf(m, __shfl_xor(m, 8));
                rmax[mt][r] = m;
            }
        if (lr == 0) {
            #pragma unroll
            for (int mt = 0; mt < 2; ++mt)
                #pragma unroll
                for (int r = 0; r < 4; ++r)
                    redM[nh*128 + mq*32 + mt*16 + lg*4 + r] = rmax[mt][r];
        }
        LGKM0(); BAR();
        float rsum[2][4];
        #pragma unroll
        for (int mt = 0; mt < 2; ++mt)
            #pragma unroll
            for (int r = 0; r < 4; ++r) {
                int t = mq*32 + mt*16 + lg*4 + r;
                float m = fmaxf(redM[t], redM[128 + t]);
                float ssum = 0.f;
                #pragma unroll
                for (int nt = 0; nt < 4; ++nt) {
                    float p = __expf(sacc[mt][nt][r] - m);
                    sacc[mt][nt][r] = p;
                    ssum += p;
                }
                ssum += __shfl_xor(ssum, 1);
                ssum += __shfl_xor(ssum, 2);
                ssum += __shfl_xor(ssum, 4);
                ssum += __shfl_xor(ssum, 8);
                rsum[mt][r] = ssum;
            }
        if (lr == 0) {
            #pragma unroll
            for (int mt = 0; mt < 2; ++mt)
                #pragma unroll
                for (int r = 0; r < 4; ++r)
                    redS[nh*128 + mq*32 + mt*16 + lg*4 + r] = rsum[mt][r];
        }
        LGKM0(); BAR();
        #pragma unroll
        for (int mt = 0; mt < 2; ++mt)
            #pragma unroll
            for (int r = 0; r < 4; ++r) {
                int t = mq*32 + mt*16 + lg*4 + r;
                float inv = 1.0f / (redS[t] + redS[128 + t]);
                #pragma unroll
                for (int nt = 0; nt < 4; ++nt) {
                    int s = nh*64 + nt*16 + lr;
                    *(unsigned short*)(lds + R_A + t*256 + ((s*2) ^ ((t&7)<<4)))
                        = f2bf(sacc[mt][nt][r] * inv);
                }
            }
    }
    LGKM0(); BAR();

    // P A-frags (live through both e-halves)
    short8 pa[2][4];
    #pragma unroll
    for (int mt = 0; mt < 2; ++mt) {
        int t2 = mq*32 + mt*16 + lr;
        #pragma unroll
        for (int ks = 0; ks < 4; ++ks)
            pa[mt][ks] = *(const short8*)(lds + R_A + t2*256 + ((ks*64 + lg*16) ^ ((t2&7)<<4)));
    }

    // ---- Ph2/Ph3: H halves (128 rows) -> OUT e-halves ----
    const float* bbp = (const float*)(ws + WS_BB + h*1024);
    #pragma unroll
    for (int eh = 0; eh < 2; ++eh) {
        // Hh = WM[eh half rows] * X^T -> R_B [128e local][128s], swz
        {
            f32x4 acc[2][4];
            #pragma unroll
            for (int i = 0; i < 2; ++i)
                #pragma unroll
                for (int jj = 0; jj < 4; ++jj) acc[i][jj] = f32x4{0.f,0.f,0.f,0.f};
            #pragma unroll
            for (int ks = 0; ks < 8; ++ks) {
                short8 wa[2];
                #pragma unroll
                for (int me = 0; me < 2; ++me)
                    wa[me] = *(const short8*)(WMh + (((eh*8 + mq*2+me)*8 + ks) << 10) + l*16);
                short8 sb[4];
                #pragma unroll
                for (int nt = 0; nt < 4; ++nt)
                    sb[nt] = *(const short8*)(Xf + (((nh*4 + nt)*8 + ks) << 10) + l*16);
                PRIO1();
                #pragma unroll
                for (int me = 0; me < 2; ++me)
                    #pragma unroll
                    for (int nt = 0; nt < 4; ++nt)
                        acc[me][nt] = __builtin_amdgcn_mfma_f32_16x16x32_bf16(wa[me], sb[nt], acc[me][nt], 0, 0, 0);
                PRIO0();
            }
            #pragma unroll
            for (int me = 0; me < 2; ++me)
                #pragma unroll
                for (int nt = 0; nt < 4; ++nt)
                    #pragma unroll
                    for (int r = 0; r < 4; ++r) {
                        int el = (mq*2+me)*16 + lg*4 + r;
                        int s  = (nh*4 + nt)*16 + lr;
                        *(unsigned short*)(lds + R_B + el*256 + ((s*2) ^ ((el&7)<<4)))
                            = f2bf(acc[me][nt][r]);
                    }
        }
        LGKM0(); BAR();
        // OUT[:, e-half] = P * Hh^T + bb
        #pragma unroll
        for (int ec = 0; ec < 2; ++ec) {
            f32x4 acc[2][2];
            #pragma unroll
            for (int i = 0; i < 2; ++i)
                #pragma unroll
                for (int jj = 0; jj < 2; ++jj) acc[i][jj] = f32x4{0.f,0.f,0.f,0.f};
            #pragma unroll
            for (int ks = 0; ks < 4; ++ks) {
                short8 hb[2];
                #pragma unroll
                for (int nt = 0; nt < 2; ++nt) {
                    int erl = (nh*4 + ec*2 + nt)*16 + lr;
                    hb[nt] = *(const short8*)(lds + R_B + erl*256 + ((ks*64 + lg*16) ^ ((erl&7)<<4)));
                }
                PRIO1();
                #pragma unroll
                for (int mt = 0; mt < 2; ++mt)
                    #pragma unroll
                    for (int nt = 0; nt < 2; ++nt)
                        acc[mt][nt] = __builtin_amdgcn_mfma_f32_16x16x32_bf16(pa[mt][ks], hb[nt], acc[mt][nt], 0, 0, 0);
                PRIO0();
            }
            #pragma unroll
            for (int nt = 0; nt < 2; ++nt) {
                int e = eh*128 + (nh*4 + ec*2 + nt)*16 + lr;
                float bbv = bbp[e];
                #pragma unroll
                for (int mt = 0; mt < 2; ++mt)
                    #pragma unroll
                    for (int r = 0; r < 4; ++r) {
                        int t = mq*32 + mt*16 + lg*4 + r;
                        out[(orow + t) * 256 + e] = acc[mt][nt][r] + bbv;
                    }
            }
        }
        if (eh == 0) { LGKM0(); BAR(); }   // protect R_B overwrite
    }
}

extern "C" void kernel_launch(void* const* d_in, const int* in_sizes, int n_in,
                              void* d_out, int out_size, void* d_ws, size_t ws_size,
                              hipStream_t stream) {
    (void)in_sizes; (void)n_in; (void)out_size; (void)ws_size; // needs ws_size >= 18948128
    const float* x  = (const float*)d_in[0];
    const float* Wq = (const float*)d_in[1];
    const float* bq = (const float*)d_in[2];
    const float* Wk = (const float*)d_in[3];
    const float* bk = (const float*)d_in[4];
    const float* Wv = (const float*)d_in[5];
    const float* bv = (const float*)d_in[6];
    const float* Wp = (const float*)d_in[7];
    const float* bp = (const float*)d_in[8];
    char* ws = (char*)d_ws;

    hipFuncSetAttribute((const void*)convert_pre,
                        hipFuncAttributeMaxDynamicSharedMemorySize, 65536);
    convert_pre<<<dim3(536), dim3(256), 65536, stream>>>(
        x, Wq, bq, Wk, bk, Wv, bv, Wp, bp, ws);

    hipFuncSetAttribute((const void*)mha_fused,
                        hipFuncAttributeMaxDynamicSharedMemorySize, LDS_SIZE);
    mha_fused<<<dim3(2048), dim3(512), LDS_SIZE, stream>>>(ws, (float*)d_out);
}

// Round 15
// 267.235 us; speedup vs baseline: 2.5244x; 1.0446x over previous
//
#include <hip/hip_runtime.h>
#include <hip/hip_bf16.h>
#include <stdint.h>

// Fused causal MHA, B=256,T=128,H=8,D=256,C=256. One block per (h,b).
// Round 15: kill redundant global operand streams. X staged once into LDS
// (fragment order is lane-linear -> global_load_lds), M/WM read exactly once
// per block via per-wave-unique col/row-group ownership. ~330KB global/block
// (was ~2MB). LDS 134KB, 1 block/CU, launch_bounds(512,1).

#define TT 128

typedef __attribute__((ext_vector_type(8))) short short8;
typedef __attribute__((ext_vector_type(4))) float f32x4;

// ---- ws map (total 18948128 B < proven-available 20054016) ----
#define WS_X    0u                       // 256 b x 64KB  X A/B-frags
#define WS_M    16777216u                // 8 h x 128KB   M^T-layout B-frags (scaled 1/16)
#define WS_WM   17825792u                // 8 h x 128KB   WM A-frags
#define WS_WB   18874368u                // 8 h x 8KB     [w2;w1] B-frags (rows 0,1), zero-filled
#define WS_BB   18939904u                // 8 h x 1KB     bb fp32
#define WS_CQ   18948096u                // 8 x 4B        cqk fp32

// ---- LDS map (134144 B, 1 block/CU) ----
#define LX     0         // X frags [64KB], lane-linear (staged via global_load_lds)
#define LT     65536     // T1 [128t][512B swz]; after softmax: P at [65536,98304),
#define LP     65536     //   H-half at [98304,131072)
#define LH     98304
#define R_UV   131072    // v[128] f32 | u[128] f32
#define R_RED  132096    // redM[256] | redS[256]
#define LDS_SIZE 134144

#define VMCNT0() asm volatile("s_waitcnt vmcnt(0)" ::: "memory")
#define LGKM0()  asm volatile("s_waitcnt lgkmcnt(0)" ::: "memory")
#define BAR()    do { asm volatile("" ::: "memory"); __builtin_amdgcn_s_barrier(); asm volatile("" ::: "memory"); } while (0)
#define PRIO1()  __builtin_amdgcn_s_setprio(1)
#define PRIO0()  __builtin_amdgcn_s_setprio(0)

typedef __attribute__((address_space(3))) uint32_t lds_u32;
typedef __attribute__((address_space(1))) const uint32_t glb_u32;

__device__ __forceinline__ unsigned short f2bf(float x) {
    union { float f; unsigned u; } v; v.f = x;
    unsigned r = v.u + 0x7FFFu + ((v.u >> 16) & 1u);
    return (unsigned short)(r >> 16);
}
__device__ __forceinline__ unsigned pk2(float a, float b) {
    return (unsigned)f2bf(a) | ((unsigned)f2bf(b) << 16);
}

// =============== convert / fold kernel (unchanged from round 9) ============
__global__ __launch_bounds__(256) void convert_pre(
    const float* __restrict__ x,
    const float* __restrict__ Wq, const float* __restrict__ bq,
    const float* __restrict__ Wk, const float* __restrict__ bk,
    const float* __restrict__ Wv, const float* __restrict__ bv,
    const float* __restrict__ Wp, const float* __restrict__ bp,
    char* __restrict__ ws)
{
    extern __shared__ char clds[];
    const int tid = threadIdx.x;
    const int bid = blockIdx.x;

    if (bid < 256) {
        const float* src = x + (size_t)bid * 32768;
        char* dst = ws + WS_X + (size_t)bid * 65536;
        for (int i = tid; i < 8192; i += 256) {
            float4 v = ((const float4*)src)[i];
            int row = i >> 6, c4 = i & 63;
            uint2 u; u.x = pk2(v.x, v.y); u.y = pk2(v.z, v.w);
            *(uint2*)(clds + row * 512 + ((c4 * 8) ^ ((row & 7) << 4))) = u;
        }
        __syncthreads();
        for (int i = tid; i < 4096; i += 256) {
            int l = i & 63, ks = (i >> 6) & 7, g = i >> 9;
            int r = g * 16 + (l & 15);
            int boff = ks * 64 + (l >> 4) * 16;
            uint4 q = *(const uint4*)(clds + r * 512 + (boff ^ ((r & 7) << 4)));
            ((uint4*)dst)[i] = q;
        }
        return;
    }
    if (bid < 384) {
        int id = bid - 256, h = id >> 4, st = id & 15;
        float* wkL = (float*)clds;
        for (int i = tid; i < 4096; i += 256) {
            int d = i >> 4, cc = i & 15;
            wkL[i] = Wk[(size_t)h * 65536 + d * 256 + st * 16 + cc];
        }
        __syncthreads();
        const int c = tid;
        float acc[16];
        #pragma unroll
        for (int j = 0; j < 16; ++j) acc[j] = 0.f;
        #pragma unroll 4
        for (int d = 0; d < 256; ++d) {
            float a = Wq[(size_t)h * 65536 + d * 256 + c];
            #pragma unroll
            for (int j = 0; j < 16; ++j) acc[j] += a * wkL[d * 16 + j];
        }
        char* base = ws + WS_M + (size_t)h * 131072;
        int ks = c >> 5, lgp = (c >> 3) & 3, jb = c & 7;
        #pragma unroll
        for (int j = 0; j < 16; ++j) {
            int cp = st * 16 + j;
            *(unsigned short*)(base + (((st * 8 + ks)) << 10)
                + ((cp & 15) + 16 * lgp) * 16 + jb * 2) = f2bf(acc[j] * 0.0625f);
        }
        return;
    }
    if (bid < 512) {
        int id = bid - 384, h = id >> 4, st = id & 15;
        float* wpL = (float*)clds;
        for (int i = tid; i < 4096; i += 256) {
            int e = i >> 8, d = i & 255;
            wpL[e * 257 + d] = Wp[(size_t)(st * 16 + e) * 256 + d];
        }
        __syncthreads();
        const int c = tid;
        float acc[16];
        #pragma unroll
        for (int j = 0; j < 16; ++j) acc[j] = 0.f;
        #pragma unroll 4
        for (int d = 0; d < 256; ++d) {
            float wv = Wv[(size_t)h * 65536 + d * 256 + c];
            #pragma unroll
            for (int j = 0; j < 16; ++j) acc[j] += wv * wpL[j * 257 + d];
        }
        char* base = ws + WS_WM + (size_t)h * 131072;
        int ks = c >> 5, lgp = (c >> 3) & 3, jb = c & 7;
        #pragma unroll
        for (int j = 0; j < 16; ++j) {
            *(unsigned short*)(base + (((st * 8 + ks)) << 10)
                + (j + 16 * lgp) * 16 + jb * 2) = f2bf(acc[j]);
        }
        return;
    }
    if (bid < 520) {
        const int h = bid - 512;
        {
            uint4 z = {0u,0u,0u,0u};
            for (int i = tid; i < 512; i += 256)
                ((uint4*)(ws + WS_WB + (size_t)h * 8192))[i] = z;
        }
        float* tK = (float*)clds;
        float* tQ = (float*)(clds + 16384);
        const int c = tid;
        float s1 = 0.f, s2 = 0.f;
        for (int d0 = 0; d0 < 256; d0 += 16) {
            __syncthreads();
            for (int i = tid; i < 1024; i += 256) {
                int row = i >> 6, c4 = i & 63;
                ((float4*)tK)[row * 64 + c4] =
                    ((const float4*)(Wk + (size_t)h * 65536 + (size_t)(d0 + row) * 256))[c4];
                ((float4*)tQ)[row * 64 + c4] =
                    ((const float4*)(Wq + (size_t)h * 65536 + (size_t)(d0 + row) * 256))[c4];
            }
            __syncthreads();
            #pragma unroll
            for (int dd = 0; dd < 16; ++dd) {
                s1 += tK[dd * 256 + c] * bq[h * 256 + d0 + dd];
                s2 += tQ[dd * 256 + c] * bk[h * 256 + d0 + dd];
            }
        }
        int ks = c >> 5, lgp = (c >> 3) & 3, jb = c & 7;
        char* base = ws + WS_WB + (size_t)h * 8192 + ks * 1024;
        *(unsigned short*)(base + (0 + 16 * lgp) * 16 + jb * 2) = f2bf(s2 * 0.0625f);
        *(unsigned short*)(base + (1 + 16 * lgp) * 16 + jb * 2) = f2bf(s1 * 0.0625f);
        float* red = (float*)(clds + 32768);
        red[tid] = bq[h * 256 + tid] * bk[h * 256 + tid];
        __syncthreads();
        if (tid == 0) {
            float cq = 0.f;
            for (int d = 0; d < 256; ++d) cq += red[d];
            *(float*)(ws + WS_CQ + h * 4) = cq * 0.0625f;
        }
        return;
    }
    {
        const int st = bid - 520;
        float* wpT = (float*)clds;
        float* bvL = (float*)(clds + 17408);
        for (int i = tid; i < 1024; i += 256) {
            int row = i >> 6, c4 = i & 63;
            float4 v = ((const float4*)(Wp + (size_t)(st * 16 + row) * 256))[c4];
            float* dstp = wpT + row * 257 + c4 * 4;
            dstp[0] = v.x; dstp[1] = v.y; dstp[2] = v.z; dstp[3] = v.w;
        }
        for (int i = tid; i < 512; i += 256)
            ((float4*)bvL)[i] = ((const float4*)bv)[i];
        __syncthreads();
        const int el = tid >> 4, dg = tid & 15;
        #pragma unroll
        for (int h = 0; h < 8; ++h) {
            float p = 0.f;
            #pragma unroll
            for (int dd = 0; dd < 16; ++dd) {
                int d = dg * 16 + dd;
                p += bvL[h * 256 + d] * wpT[el * 257 + d];
            }
            p += __shfl_xor(p, 1);
            p += __shfl_xor(p, 2);
            p += __shfl_xor(p, 4);
            p += __shfl_xor(p, 8);
            if (dg == 0)
                *(float*)(ws + WS_BB + (size_t)h * 1024 + (st * 16 + el) * 4)
                    = bp[st * 16 + el] + p;
        }
        return;
    }
}

// =============== main fused kernel =========================================
__global__ __launch_bounds__(512, 1) void mha_fused(
    const char* __restrict__ ws, float* __restrict__ out)
{
    extern __shared__ char lds[];
    const int tid = threadIdx.x;
    const int w  = tid >> 6, l = tid & 63;
    const int lg = l >> 4, lr = l & 15;
    const int mq = w & 3, nh = w >> 2;
    // XCD-aware mapping (round 14): 8 h-blocks of one b on the same XCD
    const int bid = blockIdx.x;
    const int xcd = bid & 7, j = bid >> 3;
    const int h = j & 7;
    const int b = ((j >> 3) << 3) | xcd;
    const size_t orow = ((size_t)(h * 256 + b)) * TT;

    const char* Xf  = ws + WS_X  + (size_t)b * 65536;
    const char* Mh  = ws + WS_M  + (size_t)h * 131072;
    const char* WMh = ws + WS_WM + (size_t)h * 131072;
    const char* WBh = ws + WS_WB + (size_t)h * 8192;

    // ---- stage X (64KB, lane-linear frag order) into LDS ----
    {
        const char* src = Xf + tid * 16;
        #pragma unroll
        for (int p = 0; p < 8; ++p)
            __builtin_amdgcn_global_load_lds((glb_u32*)(src + p * 8192),
                (lds_u32*)(lds + LX + tid * 16 + p * 8192), 16, 0, 0);
    }
    VMCNT0(); BAR();

    // ---- Ph0a: [v|u] = X * [w2;w1]^T  (wb streamed, xa from LDS) ----
    {
        f32x4 vacc[2] = {f32x4{0.f,0.f,0.f,0.f}, f32x4{0.f,0.f,0.f,0.f}};
        #pragma unroll
        for (int ks = 0; ks < 8; ++ks) {
            short8 wb  = *(const short8*)(WBh + (ks << 10) + l*16);
            short8 xa0 = *(const short8*)(lds + LX + (((mq*2 + 0)*8 + ks) << 10) + l*16);
            short8 xa1 = *(const short8*)(lds + LX + (((mq*2 + 1)*8 + ks) << 10) + l*16);
            vacc[0] = __builtin_amdgcn_mfma_f32_16x16x32_bf16(xa0, wb, vacc[0], 0, 0, 0);
            vacc[1] = __builtin_amdgcn_mfma_f32_16x16x32_bf16(xa1, wb, vacc[1], 0, 0, 0);
        }
        if (nh == 0 && lr < 2) {
            #pragma unroll
            for (int mt = 0; mt < 2; ++mt)
                #pragma unroll
                for (int r = 0; r < 4; ++r) {
                    int t = mq*32 + mt*16 + lg*4 + r;
                    *(float*)(lds + R_UV + lr*512 + t*4) = vacc[mt][r];
                }
        }
    }

    // ---- Ph0b: T1 = X * N ; wave w owns col-groups {2w, 2w+1}; M read ONCE ----
    #pragma unroll
    for (int pass = 0; pass < 2; ++pass) {
        const int ga = w*2 + pass;
        f32x4 acc[8];
        #pragma unroll
        for (int i = 0; i < 8; ++i) acc[i] = f32x4{0.f,0.f,0.f,0.f};
        #pragma unroll
        for (int ks = 0; ks < 8; ++ks) {
            short8 nb = *(const short8*)(Mh + (((ga*8 + ks)) << 10) + l*16);
            PRIO1();
            #pragma unroll
            for (int mt = 0; mt < 8; ++mt) {
                short8 xa = *(const short8*)(lds + LX + (((mt*8 + ks)) << 10) + l*16);
                acc[mt] = __builtin_amdgcn_mfma_f32_16x16x32_bf16(xa, nb, acc[mt], 0, 0, 0);
            }
            PRIO0();
        }
        #pragma unroll
        for (int mt = 0; mt < 8; ++mt)
            #pragma unroll
            for (int r = 0; r < 4; ++r) {
                int t = mt*16 + lg*4 + r;
                int c = ga*16 + lr;
                *(unsigned short*)(lds + LT + t*512 + ((c*2) ^ ((t&7)<<4)))
                    = f2bf(acc[mt][r]);
            }
    }
    LGKM0(); BAR();

    // ---- Ph1: S = T1 * X^T (ta from LT, sb from LX) ----
    f32x4 sacc[2][4];
    #pragma unroll
    for (int i = 0; i < 2; ++i)
        #pragma unroll
        for (int jj = 0; jj < 4; ++jj) sacc[i][jj] = f32x4{0.f,0.f,0.f,0.f};
    #pragma unroll
    for (int ks2 = 0; ks2 < 8; ++ks2) {
        short8 ta[2];
        #pragma unroll
        for (int mt = 0; mt < 2; ++mt) {
            int t2 = mq*32 + mt*16 + lr;
            ta[mt] = *(const short8*)(lds + LT + t2*512 + ((ks2*64 + lg*16) ^ ((t2&7)<<4)));
        }
        short8 sb[4];
        #pragma unroll
        for (int nt = 0; nt < 4; ++nt)
            sb[nt] = *(const short8*)(lds + LX + (((nh*4+nt)*8 + ks2) << 10) + l*16);
        PRIO1();
        #pragma unroll
        for (int mt = 0; mt < 2; ++mt)
            #pragma unroll
            for (int nt = 0; nt < 4; ++nt)
                sacc[mt][nt] = __builtin_amdgcn_mfma_f32_16x16x32_bf16(ta[mt], sb[nt], sacc[mt][nt], 0, 0, 0);
        PRIO0();
    }

    // ---- softmax: bias add, mask, max, exp, sum, P -> LP ----
    {
        const float cq = *(const float*)(ws + WS_CQ + h*4);
        float uu[4];
        #pragma unroll
        for (int nt = 0; nt < 4; ++nt)
            uu[nt] = *(const float*)(lds + R_UV + 512 + (nh*64 + nt*16 + lr)*4);
        float* redM = (float*)(lds + R_RED);
        float* redS = redM + 256;
        float rmax[2][4];
        #pragma unroll
        for (int mt = 0; mt < 2; ++mt)
            #pragma unroll
            for (int r = 0; r < 4; ++r) {
                int t = mq*32 + mt*16 + lg*4 + r;
                float vt = *(const float*)(lds + R_UV + t*4) + cq;
                float m = -1e30f;
                #pragma unroll
                for (int nt = 0; nt < 4; ++nt) {
                    int s = nh*64 + nt*16 + lr;
                    float sv = sacc[mt][nt][r] + vt + uu[nt];
                    if (s > t) sv = -1e30f;
                    sacc[mt][nt][r] = sv;
                    m = fmaxf(m, sv);
                }
                m = fmaxf(m, __shfl_xor(m, 1));
                m = fmaxf(m, __shfl_xor(m, 2));
                m = fmaxf(m, __shfl_xor(m, 4));
                m = fmaxf(m, __shfl_xor(m, 8));
                rmax[mt][r] = m;
            }
        if (lr == 0) {
            #pragma unroll
            for (int mt = 0; mt < 2; ++mt)
                #pragma unroll
                for (int r = 0; r < 4; ++r)
                    redM[nh*128 + mq*32 + mt*16 + lg*4 + r] = rmax[mt][r];
        }
        LGKM0(); BAR();
        float rsum[2][4];
        #pragma unroll
        for (int mt = 0; mt < 2; ++mt)
            #pragma unroll
            for (int r = 0; r < 4; ++r) {
                int t = mq*32 + mt*16 + lg*4 + r;
                float m = fmaxf(redM[t], redM[128 + t]);
                float ssum = 0.f;
                #pragma unroll
                for (int nt = 0; nt < 4; ++nt) {
                    float p = __expf(sacc[mt][nt][r] - m);
                    sacc[mt][nt][r] = p;
                    ssum += p;
                }
                ssum += __shfl_xor(ssum, 1);
                ssum += __shfl_xor(ssum, 2);
                ssum += __shfl_xor(ssum, 4);
                ssum += __shfl_xor(ssum, 8);
                rsum[mt][r] = ssum;
            }
        if (lr == 0) {
            #pragma unroll
            for (int mt = 0; mt < 2; ++mt)
                #pragma unroll
                for (int r = 0; r < 4; ++r)
                    redS[nh*128 + mq*32 + mt*16 + lg*4 + r] = rsum[mt][r];
        }
        LGKM0(); BAR();
        #pragma unroll
        for (int mt = 0; mt < 2; ++mt)
            #pragma unroll
            for (int r = 0; r < 4; ++r) {
                int t = mq*32 + mt*16 + lg*4 + r;
                float inv = 1.0f / (redS[t] + redS[128 + t]);
                #pragma unroll
                for (int nt = 0; nt < 4; ++nt) {
                    int s = nh*64 + nt*16 + lr;
                    *(unsigned short*)(lds + LP + t*256 + ((s*2) ^ ((t&7)<<4)))
                        = f2bf(sacc[mt][nt][r] * inv);
                }
            }
    }
    LGKM0(); BAR();

    // P A-frags (live through both e-halves)
    short8 pa[2][4];
    #pragma unroll
    for (int mt = 0; mt < 2; ++mt) {
        int t2 = mq*32 + mt*16 + lr;
        #pragma unroll
        for (int ks = 0; ks < 4; ++ks)
            pa[mt][ks] = *(const short8*)(lds + LP + t2*256 + ((ks*64 + lg*16) ^ ((t2&7)<<4)));
    }

    // ---- Ph2/Ph3: per e-half; wave w owns e-group eh*8+w -> WM read ONCE ----
    const float* bbp = (const float*)(ws + WS_BB + h*1024);
    #pragma unroll
    for (int eh = 0; eh < 2; ++eh) {
        {
            f32x4 acc[8];
            #pragma unroll
            for (int i = 0; i < 8; ++i) acc[i] = f32x4{0.f,0.f,0.f,0.f};
            #pragma unroll
            for (int ks = 0; ks < 8; ++ks) {
                short8 wa = *(const short8*)(WMh + ((((eh*8 + w)*8 + ks)) << 10) + l*16);
                PRIO1();
                #pragma unroll
                for (int nt = 0; nt < 8; ++nt) {
                    short8 sb = *(const short8*)(lds + LX + (((nt*8 + ks)) << 10) + l*16);
                    acc[nt] = __builtin_amdgcn_mfma_f32_16x16x32_bf16(wa, sb, acc[nt], 0, 0, 0);
                }
                PRIO0();
            }
            #pragma unroll
            for (int nt = 0; nt < 8; ++nt)
                #pragma unroll
                for (int r = 0; r < 4; ++r) {
                    int el = w*16 + lg*4 + r;
                    int s  = nt*16 + lr;
                    *(unsigned short*)(lds + LH + el*256 + ((s*2) ^ ((el&7)<<4)))
                        = f2bf(acc[nt][r]);
                }
        }
        LGKM0(); BAR();
        // OUT[:, e-half] = P * Hh^T + bb
        #pragma unroll
        for (int ec = 0; ec < 2; ++ec) {
            f32x4 acc[2][2];
            #pragma unroll
            for (int i = 0; i < 2; ++i)
                #pragma unroll
                for (int jj = 0; jj < 2; ++jj) acc[i][jj] = f32x4{0.f,0.f,0.f,0.f};
            #pragma unroll
            for (int ks = 0; ks < 4; ++ks) {
                short8 hb[2];
                #pragma unroll
                for (int nt = 0; nt < 2; ++nt) {
                    int erl = (nh*4 + ec*2 + nt)*16 + lr;
                    hb[nt] = *(const short8*)(lds + LH + erl*256 + ((ks*64 + lg*16) ^ ((erl&7)<<4)));
                }
                PRIO1();
                #pragma unroll
                for (int mt = 0; mt < 2; ++mt)
                    #pragma unroll
                    for (int nt = 0; nt < 2; ++nt)
                        acc[mt][nt] = __builtin_amdgcn_mfma_f32_16x16x32_bf16(pa[mt][ks], hb[nt], acc[mt][nt], 0, 0, 0);
                PRIO0();
            }
            #pragma unroll
            for (int nt = 0; nt < 2; ++nt) {
                int e = eh*128 + (nh*4 + ec*2 + nt)*16 + lr;
                float bbv = bbp[e];
                #pragma unroll
                for (int mt = 0; mt < 2; ++mt)
                    #pragma unroll
                    for (int r = 0; r < 4; ++r) {
                        int t = mq*32 + mt*16 + lg*4 + r;
                        out[(orow + t) * 256 + e] = acc[mt][nt][r] + bbv;
                    }
            }
        }
        if (eh == 0) { LGKM0(); BAR(); }   // protect LH overwrite
    }
}

extern "C" void kernel_launch(void* const* d_in, const int* in_sizes, int n_in,
                              void* d_out, int out_size, void* d_ws, size_t ws_size,
                              hipStream_t stream) {
    (void)in_sizes; (void)n_in; (void)out_size; (void)ws_size; // needs ws_size >= 18948128
    const float* x  = (const float*)d_in[0];
    const float* Wq = (const float*)d_in[1];
    const float* bq = (const float*)d_in[2];
    const float* Wk = (const float*)d_in[3];
    const float* bk = (const float*)d_in[4];
    const float* Wv = (const float*)d_in[5];
    const float* bv = (const float*)d_in[6];
    const float* Wp = (const float*)d_in[7];
    const float* bp = (const float*)d_in[8];
    char* ws = (char*)d_ws;

    hipFuncSetAttribute((const void*)convert_pre,
                        hipFuncAttributeMaxDynamicSharedMemorySize, 65536);
    convert_pre<<<dim3(536), dim3(256), 65536, stream>>>(
        x, Wq, bq, Wk, bk, Wv, bv, Wp, bp, ws);

    hipFuncSetAttribute((const void*)mha_fused,
                        hipFuncAttributeMaxDynamicSharedMemorySize, LDS_SIZE);
    mha_fused<<<dim3(2048), dim3(512), LDS_SIZE, stream>>>(ws, (float*)d_out);
}

// Round 16
// 238.965 us; speedup vs baseline: 2.8230x; 1.1183x over previous
//
#include <hip/hip_runtime.h>
#include <hip/hip_bf16.h>
#include <stdint.h>

// Fused causal MHA, B=256,T=128,H=8,D=256,C=256. One block per (h,b).
// Round 16: 1024-thread blocks (16 waves -> 4 waves/SIMD, 2x latency hiding).
// Wave = (mq = w&7: 16-row t-group, nh = w>>3: s/e-half). Same algebraic fold,
// same 134KB LDS map, same phase structure as round 15; per-wave work halved.

#define TT 128

typedef __attribute__((ext_vector_type(8))) short short8;
typedef __attribute__((ext_vector_type(4))) float f32x4;

// ---- ws map (total 18948128 B < proven-available 20054016) ----
#define WS_X    0u                       // 256 b x 64KB  X A/B-frags
#define WS_M    16777216u                // 8 h x 128KB   M^T-layout B-frags (scaled 1/16)
#define WS_WM   17825792u                // 8 h x 128KB   WM A-frags
#define WS_WB   18874368u                // 8 h x 8KB     [w2;w1] B-frags (rows 0,1), zero-filled
#define WS_BB   18939904u                // 8 h x 1KB     bb fp32
#define WS_CQ   18948096u                // 8 x 4B        cqk fp32

// ---- LDS map (134144 B, 1 block/CU) ----
#define LX     0         // X frags [64KB], lane-linear (staged via global_load_lds)
#define LT     65536     // T1 [128t][512B swz]; after softmax: P at [65536,98304)
#define LP     65536
#define LH     98304     // H-half [128e][256B swz]
#define R_UV   131072    // v[128] f32 | u[128] f32
#define R_RED  132096    // redM[256] | redS[256]
#define LDS_SIZE 134144

#define VMCNT0() asm volatile("s_waitcnt vmcnt(0)" ::: "memory")
#define LGKM0()  asm volatile("s_waitcnt lgkmcnt(0)" ::: "memory")
#define BAR()    do { asm volatile("" ::: "memory"); __builtin_amdgcn_s_barrier(); asm volatile("" ::: "memory"); } while (0)
#define PRIO1()  __builtin_amdgcn_s_setprio(1)
#define PRIO0()  __builtin_amdgcn_s_setprio(0)

typedef __attribute__((address_space(3))) uint32_t lds_u32;
typedef __attribute__((address_space(1))) const uint32_t glb_u32;

__device__ __forceinline__ unsigned short f2bf(float x) {
    union { float f; unsigned u; } v; v.f = x;
    unsigned r = v.u + 0x7FFFu + ((v.u >> 16) & 1u);
    return (unsigned short)(r >> 16);
}
__device__ __forceinline__ unsigned pk2(float a, float b) {
    return (unsigned)f2bf(a) | ((unsigned)f2bf(b) << 16);
}

// =============== convert / fold kernel (unchanged from round 9) ============
__global__ __launch_bounds__(256) void convert_pre(
    const float* __restrict__ x,
    const float* __restrict__ Wq, const float* __restrict__ bq,
    const float* __restrict__ Wk, const float* __restrict__ bk,
    const float* __restrict__ Wv, const float* __restrict__ bv,
    const float* __restrict__ Wp, const float* __restrict__ bp,
    char* __restrict__ ws)
{
    extern __shared__ char clds[];
    const int tid = threadIdx.x;
    const int bid = blockIdx.x;

    if (bid < 256) {
        const float* src = x + (size_t)bid * 32768;
        char* dst = ws + WS_X + (size_t)bid * 65536;
        for (int i = tid; i < 8192; i += 256) {
            float4 v = ((const float4*)src)[i];
            int row = i >> 6, c4 = i & 63;
            uint2 u; u.x = pk2(v.x, v.y); u.y = pk2(v.z, v.w);
            *(uint2*)(clds + row * 512 + ((c4 * 8) ^ ((row & 7) << 4))) = u;
        }
        __syncthreads();
        for (int i = tid; i < 4096; i += 256) {
            int l = i & 63, ks = (i >> 6) & 7, g = i >> 9;
            int r = g * 16 + (l & 15);
            int boff = ks * 64 + (l >> 4) * 16;
            uint4 q = *(const uint4*)(clds + r * 512 + (boff ^ ((r & 7) << 4)));
            ((uint4*)dst)[i] = q;
        }
        return;
    }
    if (bid < 384) {
        int id = bid - 256, h = id >> 4, st = id & 15;
        float* wkL = (float*)clds;
        for (int i = tid; i < 4096; i += 256) {
            int d = i >> 4, cc = i & 15;
            wkL[i] = Wk[(size_t)h * 65536 + d * 256 + st * 16 + cc];
        }
        __syncthreads();
        const int c = tid;
        float acc[16];
        #pragma unroll
        for (int j = 0; j < 16; ++j) acc[j] = 0.f;
        #pragma unroll 4
        for (int d = 0; d < 256; ++d) {
            float a = Wq[(size_t)h * 65536 + d * 256 + c];
            #pragma unroll
            for (int j = 0; j < 16; ++j) acc[j] += a * wkL[d * 16 + j];
        }
        char* base = ws + WS_M + (size_t)h * 131072;
        int ks = c >> 5, lgp = (c >> 3) & 3, jb = c & 7;
        #pragma unroll
        for (int j = 0; j < 16; ++j) {
            int cp = st * 16 + j;
            *(unsigned short*)(base + (((st * 8 + ks)) << 10)
                + ((cp & 15) + 16 * lgp) * 16 + jb * 2) = f2bf(acc[j] * 0.0625f);
        }
        return;
    }
    if (bid < 512) {
        int id = bid - 384, h = id >> 4, st = id & 15;
        float* wpL = (float*)clds;
        for (int i = tid; i < 4096; i += 256) {
            int e = i >> 8, d = i & 255;
            wpL[e * 257 + d] = Wp[(size_t)(st * 16 + e) * 256 + d];
        }
        __syncthreads();
        const int c = tid;
        float acc[16];
        #pragma unroll
        for (int j = 0; j < 16; ++j) acc[j] = 0.f;
        #pragma unroll 4
        for (int d = 0; d < 256; ++d) {
            float wv = Wv[(size_t)h * 65536 + d * 256 + c];
            #pragma unroll
            for (int j = 0; j < 16; ++j) acc[j] += wv * wpL[j * 257 + d];
        }
        char* base = ws + WS_WM + (size_t)h * 131072;
        int ks = c >> 5, lgp = (c >> 3) & 3, jb = c & 7;
        #pragma unroll
        for (int j = 0; j < 16; ++j) {
            *(unsigned short*)(base + (((st * 8 + ks)) << 10)
                + (j + 16 * lgp) * 16 + jb * 2) = f2bf(acc[j]);
        }
        return;
    }
    if (bid < 520) {
        const int h = bid - 512;
        {
            uint4 z = {0u,0u,0u,0u};
            for (int i = tid; i < 512; i += 256)
                ((uint4*)(ws + WS_WB + (size_t)h * 8192))[i] = z;
        }
        float* tK = (float*)clds;
        float* tQ = (float*)(clds + 16384);
        const int c = tid;
        float s1 = 0.f, s2 = 0.f;
        for (int d0 = 0; d0 < 256; d0 += 16) {
            __syncthreads();
            for (int i = tid; i < 1024; i += 256) {
                int row = i >> 6, c4 = i & 63;
                ((float4*)tK)[row * 64 + c4] =
                    ((const float4*)(Wk + (size_t)h * 65536 + (size_t)(d0 + row) * 256))[c4];
                ((float4*)tQ)[row * 64 + c4] =
                    ((const float4*)(Wq + (size_t)h * 65536 + (size_t)(d0 + row) * 256))[c4];
            }
            __syncthreads();
            #pragma unroll
            for (int dd = 0; dd < 16; ++dd) {
                s1 += tK[dd * 256 + c] * bq[h * 256 + d0 + dd];
                s2 += tQ[dd * 256 + c] * bk[h * 256 + d0 + dd];
            }
        }
        int ks = c >> 5, lgp = (c >> 3) & 3, jb = c & 7;
        char* base = ws + WS_WB + (size_t)h * 8192 + ks * 1024;
        *(unsigned short*)(base + (0 + 16 * lgp) * 16 + jb * 2) = f2bf(s2 * 0.0625f);
        *(unsigned short*)(base + (1 + 16 * lgp) * 16 + jb * 2) = f2bf(s1 * 0.0625f);
        float* red = (float*)(clds + 32768);
        red[tid] = bq[h * 256 + tid] * bk[h * 256 + tid];
        __syncthreads();
        if (tid == 0) {
            float cq = 0.f;
            for (int d = 0; d < 256; ++d) cq += red[d];
            *(float*)(ws + WS_CQ + h * 4) = cq * 0.0625f;
        }
        return;
    }
    {
        const int st = bid - 520;
        float* wpT = (float*)clds;
        float* bvL = (float*)(clds + 17408);
        for (int i = tid; i < 1024; i += 256) {
            int row = i >> 6, c4 = i & 63;
            float4 v = ((const float4*)(Wp + (size_t)(st * 16 + row) * 256))[c4];
            float* dstp = wpT + row * 257 + c4 * 4;
            dstp[0] = v.x; dstp[1] = v.y; dstp[2] = v.z; dstp[3] = v.w;
        }
        for (int i = tid; i < 512; i += 256)
            ((float4*)bvL)[i] = ((const float4*)bv)[i];
        __syncthreads();
        const int el = tid >> 4, dg = tid & 15;
        #pragma unroll
        for (int h = 0; h < 8; ++h) {
            float p = 0.f;
            #pragma unroll
            for (int dd = 0; dd < 16; ++dd) {
                int d = dg * 16 + dd;
                p += bvL[h * 256 + d] * wpT[el * 257 + d];
            }
            p += __shfl_xor(p, 1);
            p += __shfl_xor(p, 2);
            p += __shfl_xor(p, 4);
            p += __shfl_xor(p, 8);
            if (dg == 0)
                *(float*)(ws + WS_BB + (size_t)h * 1024 + (st * 16 + el) * 4)
                    = bp[st * 16 + el] + p;
        }
        return;
    }
}

// =============== main fused kernel: 1024 threads = 16 waves ================
__global__ __launch_bounds__(1024, 1) void mha_fused(
    const char* __restrict__ ws, float* __restrict__ out)
{
    extern __shared__ char lds[];
    const int tid = threadIdx.x;
    const int w  = tid >> 6, l = tid & 63;
    const int lg = l >> 4, lr = l & 15;
    const int mq = w & 7, nh = w >> 3;      // 8 t-groups x 2 halves
    const int bid = blockIdx.x;
    const int xcd = bid & 7, j = bid >> 3;
    const int h = j & 7;
    const int b = ((j >> 3) << 3) | xcd;
    const size_t orow = ((size_t)(h * 256 + b)) * TT;

    const char* Xf  = ws + WS_X  + (size_t)b * 65536;
    const char* Mh  = ws + WS_M  + (size_t)h * 131072;
    const char* WMh = ws + WS_WM + (size_t)h * 131072;
    const char* WBh = ws + WS_WB + (size_t)h * 8192;

    // ---- stage X (64KB, lane-linear frag order) into LDS ----
    {
        const char* src = Xf + tid * 16;
        #pragma unroll
        for (int p = 0; p < 4; ++p)
            __builtin_amdgcn_global_load_lds((glb_u32*)(src + p * 16384),
                (lds_u32*)(lds + LX + tid * 16 + p * 16384), 16, 0, 0);
    }
    VMCNT0(); BAR();

    // ---- Ph0a: [v|u] = X * [w2;w1]^T (nh==0 waves only; 8 MFMA/wave) ----
    if (nh == 0) {
        f32x4 vacc = f32x4{0.f,0.f,0.f,0.f};
        #pragma unroll
        for (int ks = 0; ks < 8; ++ks) {
            short8 wb = *(const short8*)(WBh + (ks << 10) + l*16);
            short8 xa = *(const short8*)(lds + LX + (((mq*8 + ks)) << 10) + l*16);
            vacc = __builtin_amdgcn_mfma_f32_16x16x32_bf16(xa, wb, vacc, 0, 0, 0);
        }
        if (lr < 2) {
            #pragma unroll
            for (int r = 0; r < 4; ++r) {
                int t = mq*16 + lg*4 + r;
                *(float*)(lds + R_UV + lr*512 + t*4) = vacc[r];
            }
        }
    }

    // ---- Ph0b: T1 = X * N ; wave w owns col-group w (M read once) ----
    {
        f32x4 acc[8];
        #pragma unroll
        for (int i = 0; i < 8; ++i) acc[i] = f32x4{0.f,0.f,0.f,0.f};
        #pragma unroll
        for (int ks = 0; ks < 8; ++ks) {
            short8 nb = *(const short8*)(Mh + (((w*8 + ks)) << 10) + l*16);
            PRIO1();
            #pragma unroll
            for (int mt = 0; mt < 8; ++mt) {
                short8 xa = *(const short8*)(lds + LX + (((mt*8 + ks)) << 10) + l*16);
                acc[mt] = __builtin_amdgcn_mfma_f32_16x16x32_bf16(xa, nb, acc[mt], 0, 0, 0);
            }
            PRIO0();
        }
        #pragma unroll
        for (int mt = 0; mt < 8; ++mt)
            #pragma unroll
            for (int r = 0; r < 4; ++r) {
                int t = mt*16 + lg*4 + r;
                int c = w*16 + lr;
                *(unsigned short*)(lds + LT + t*512 + ((c*2) ^ ((t&7)<<4)))
                    = f2bf(acc[mt][r]);
            }
    }
    LGKM0(); BAR();

    // ---- Ph1: S = T1 * X^T ; wave (mq: 16 t, nh: 64 s) ----
    f32x4 sacc[4];
    #pragma unroll
    for (int i = 0; i < 4; ++i) sacc[i] = f32x4{0.f,0.f,0.f,0.f};
    #pragma unroll
    for (int ks2 = 0; ks2 < 8; ++ks2) {
        int t2 = mq*16 + lr;
        short8 ta = *(const short8*)(lds + LT + t2*512 + ((ks2*64 + lg*16) ^ ((t2&7)<<4)));
        short8 sb[4];
        #pragma unroll
        for (int nt = 0; nt < 4; ++nt)
            sb[nt] = *(const short8*)(lds + LX + (((nh*4+nt)*8 + ks2) << 10) + l*16);
        PRIO1();
        #pragma unroll
        for (int nt = 0; nt < 4; ++nt)
            sacc[nt] = __builtin_amdgcn_mfma_f32_16x16x32_bf16(ta, sb[nt], sacc[nt], 0, 0, 0);
        PRIO0();
    }

    // ---- softmax: bias add, mask, max, exp, sum, P -> LP ----
    {
        const float cq = *(const float*)(ws + WS_CQ + h*4);
        float uu[4];
        #pragma unroll
        for (int nt = 0; nt < 4; ++nt)
            uu[nt] = *(const float*)(lds + R_UV + 512 + (nh*64 + nt*16 + lr)*4);
        float* redM = (float*)(lds + R_RED);
        float* redS = redM + 256;
        float rmax[4];
        #pragma unroll
        for (int r = 0; r < 4; ++r) {
            int t = mq*16 + lg*4 + r;
            float vt = *(const float*)(lds + R_UV + t*4) + cq;
            float m = -1e30f;
            #pragma unroll
            for (int nt = 0; nt < 4; ++nt) {
                int s = nh*64 + nt*16 + lr;
                float sv = sacc[nt][r] + vt + uu[nt];
                if (s > t) sv = -1e30f;
                sacc[nt][r] = sv;
                m = fmaxf(m, sv);
            }
            m = fmaxf(m, __shfl_xor(m, 1));
            m = fmaxf(m, __shfl_xor(m, 2));
            m = fmaxf(m, __shfl_xor(m, 4));
            m = fmaxf(m, __shfl_xor(m, 8));
            rmax[r] = m;
        }
        if (lr == 0) {
            #pragma unroll
            for (int r = 0; r < 4; ++r)
                redM[nh*128 + mq*16 + lg*4 + r] = rmax[r];
        }
        LGKM0(); BAR();
        float rsum[4];
        #pragma unroll
        for (int r = 0; r < 4; ++r) {
            int t = mq*16 + lg*4 + r;
            float m = fmaxf(redM[t], redM[128 + t]);
            float ssum = 0.f;
            #pragma unroll
            for (int nt = 0; nt < 4; ++nt) {
                float p = __expf(sacc[nt][r] - m);
                sacc[nt][r] = p;
                ssum += p;
            }
            ssum += __shfl_xor(ssum, 1);
            ssum += __shfl_xor(ssum, 2);
            ssum += __shfl_xor(ssum, 4);
            ssum += __shfl_xor(ssum, 8);
            rsum[r] = ssum;
        }
        if (lr == 0) {
            #pragma unroll
            for (int r = 0; r < 4; ++r)
                redS[nh*128 + mq*16 + lg*4 + r] = rsum[r];
        }
        LGKM0(); BAR();
        #pragma unroll
        for (int r = 0; r < 4; ++r) {
            int t = mq*16 + lg*4 + r;
            float inv = 1.0f / (redS[t] + redS[128 + t]);
            #pragma unroll
            for (int nt = 0; nt < 4; ++nt) {
                int s = nh*64 + nt*16 + lr;
                *(unsigned short*)(lds + LP + t*256 + ((s*2) ^ ((t&7)<<4)))
                    = f2bf(sacc[nt][r] * inv);
            }
        }
    }
    LGKM0(); BAR();

    // P A-frags for this wave's t-group (full 128 s)
    short8 pa[4];
    {
        int t2 = mq*16 + lr;
        #pragma unroll
        for (int ks = 0; ks < 4; ++ks)
            pa[ks] = *(const short8*)(lds + LP + t2*256 + ((ks*64 + lg*16) ^ ((t2&7)<<4)));
    }

    // ---- Ph2/Ph3: per e-half; wave (mq: e-group, nh: s-half) ----
    const float* bbp = (const float*)(ws + WS_BB + h*1024);
    #pragma unroll
    for (int eh = 0; eh < 2; ++eh) {
        {
            f32x4 acc[4];
            #pragma unroll
            for (int i = 0; i < 4; ++i) acc[i] = f32x4{0.f,0.f,0.f,0.f};
            #pragma unroll
            for (int ks = 0; ks < 8; ++ks) {
                short8 wa = *(const short8*)(WMh + ((((eh*8 + mq)*8 + ks)) << 10) + l*16);
                PRIO1();
                #pragma unroll
                for (int nt = 0; nt < 4; ++nt) {
                    short8 sb = *(const short8*)(lds + LX + ((((nh*4+nt)*8 + ks)) << 10) + l*16);
                    acc[nt] = __builtin_amdgcn_mfma_f32_16x16x32_bf16(wa, sb, acc[nt], 0, 0, 0);
                }
                PRIO0();
            }
            #pragma unroll
            for (int nt = 0; nt < 4; ++nt)
                #pragma unroll
                for (int r = 0; r < 4; ++r) {
                    int el = mq*16 + lg*4 + r;
                    int s  = (nh*4+nt)*16 + lr;
                    *(unsigned short*)(lds + LH + el*256 + ((s*2) ^ ((el&7)<<4)))
                        = f2bf(acc[nt][r]);
                }
        }
        LGKM0(); BAR();
        // OUT[:, e-half] = P * Hh^T + bb ; wave covers (t-group mq) x (e nh-half)
        #pragma unroll
        for (int ec = 0; ec < 2; ++ec) {
            f32x4 acc[2];
            acc[0] = f32x4{0.f,0.f,0.f,0.f};
            acc[1] = f32x4{0.f,0.f,0.f,0.f};
            #pragma unroll
            for (int ks = 0; ks < 4; ++ks) {
                short8 hb[2];
                #pragma unroll
                for (int nt = 0; nt < 2; ++nt) {
                    int erl = nh*64 + (ec*2 + nt)*16 + lr;
                    hb[nt] = *(const short8*)(lds + LH + erl*256 + ((ks*64 + lg*16) ^ ((erl&7)<<4)));
                }
                PRIO1();
                #pragma unroll
                for (int nt = 0; nt < 2; ++nt)
                    acc[nt] = __builtin_amdgcn_mfma_f32_16x16x32_bf16(pa[ks], hb[nt], acc[nt], 0, 0, 0);
                PRIO0();
            }
            #pragma unroll
            for (int nt = 0; nt < 2; ++nt) {
                int e = eh*128 + nh*64 + (ec*2 + nt)*16 + lr;
                float bbv = bbp[e];
                #pragma unroll
                for (int r = 0; r < 4; ++r) {
                    int t = mq*16 + lg*4 + r;
                    out[(orow + t) * 256 + e] = acc[nt][r] + bbv;
                }
            }
        }
        if (eh == 0) { LGKM0(); BAR(); }   // protect LH overwrite
    }
}

extern "C" void kernel_launch(void* const* d_in, const int* in_sizes, int n_in,
                              void* d_out, int out_size, void* d_ws, size_t ws_size,
                              hipStream_t stream) {
    (void)in_sizes; (void)n_in; (void)out_size; (void)ws_size; // needs ws_size >= 18948128
    const float* x  = (const float*)d_in[0];
    const float* Wq = (const float*)d_in[1];
    const float* bq = (const float*)d_in[2];
    const float* Wk = (const float*)d_in[3];
    const float* bk = (const float*)d_in[4];
    const float* Wv = (const float*)d_in[5];
    const float* bv = (const float*)d_in[6];
    const float* Wp = (const float*)d_in[7];
    const float* bp = (const float*)d_in[8];
    char* ws = (char*)d_ws;

    hipFuncSetAttribute((const void*)convert_pre,
                        hipFuncAttributeMaxDynamicSharedMemorySize, 65536);
    convert_pre<<<dim3(536), dim3(256), 65536, stream>>>(
        x, Wq, bq, Wk, bk, Wv, bv, Wp, bp, ws);

    hipFuncSetAttribute((const void*)mha_fused,
                        hipFuncAttributeMaxDynamicSharedMemorySize, LDS_SIZE);
    mha_fused<<<dim3(2048), dim3(1024), LDS_SIZE, stream>>>(ws, (float*)d_out);
}

// Round 17
// 236.291 us; speedup vs baseline: 2.8550x; 1.0113x over previous
//
#include <hip/hip_runtime.h>
#include <hip/hip_bf16.h>
#include <stdint.h>

// Fused causal MHA, B=256,T=128,H=8,D=256,C=256. One block per (h,b).
// Round 17: round-16 (16-wave blocks, 44% occ) + square register tiles in
// Ph0b (4tx2c) and Ph2 (2ex2s) to halve LDS operand traffic, + vectorized
// convert_pre inner loops (float4 broadcast reads; Wp transposed+padded).

#define TT 128

typedef __attribute__((ext_vector_type(8))) short short8;
typedef __attribute__((ext_vector_type(4))) float f32x4;

// ---- ws map (total 18948128 B < proven-available 20054016) ----
#define WS_X    0u                       // 256 b x 64KB  X A/B-frags
#define WS_M    16777216u                // 8 h x 128KB   M^T-layout B-frags (scaled 1/16)
#define WS_WM   17825792u                // 8 h x 128KB   WM A-frags
#define WS_WB   18874368u                // 8 h x 8KB     [w2;w1] B-frags (rows 0,1), zero-filled
#define WS_BB   18939904u                // 8 h x 1KB     bb fp32
#define WS_CQ   18948096u                // 8 x 4B        cqk fp32

// ---- LDS map (134144 B, 1 block/CU) ----
#define LX     0         // X frags [64KB], lane-linear (staged via global_load_lds)
#define LT     65536     // T1 [128t][512B swz]; after softmax: P at [65536,98304)
#define LP     65536
#define LH     98304     // H-half [128e][256B swz]
#define R_UV   131072    // v[128] f32 | u[128] f32
#define R_RED  132096    // redM[256] | redS[256]
#define LDS_SIZE 134144

#define VMCNT0() asm volatile("s_waitcnt vmcnt(0)" ::: "memory")
#define LGKM0()  asm volatile("s_waitcnt lgkmcnt(0)" ::: "memory")
#define BAR()    do { asm volatile("" ::: "memory"); __builtin_amdgcn_s_barrier(); asm volatile("" ::: "memory"); } while (0)
#define PRIO1()  __builtin_amdgcn_s_setprio(1)
#define PRIO0()  __builtin_amdgcn_s_setprio(0)

typedef __attribute__((address_space(3))) uint32_t lds_u32;
typedef __attribute__((address_space(1))) const uint32_t glb_u32;

__device__ __forceinline__ unsigned short f2bf(float x) {
    union { float f; unsigned u; } v; v.f = x;
    unsigned r = v.u + 0x7FFFu + ((v.u >> 16) & 1u);
    return (unsigned short)(r >> 16);
}
__device__ __forceinline__ unsigned pk2(float a, float b) {
    return (unsigned)f2bf(a) | ((unsigned)f2bf(b) << 16);
}

// =============== convert / fold kernel =====================================
__global__ __launch_bounds__(256) void convert_pre(
    const float* __restrict__ x,
    const float* __restrict__ Wq, const float* __restrict__ bq,
    const float* __restrict__ Wk, const float* __restrict__ bk,
    const float* __restrict__ Wv, const float* __restrict__ bv,
    const float* __restrict__ Wp, const float* __restrict__ bp,
    char* __restrict__ ws)
{
    extern __shared__ char clds[];
    const int tid = threadIdx.x;
    const int bid = blockIdx.x;

    if (bid < 256) {
        const float* src = x + (size_t)bid * 32768;
        char* dst = ws + WS_X + (size_t)bid * 65536;
        for (int i = tid; i < 8192; i += 256) {
            float4 v = ((const float4*)src)[i];
            int row = i >> 6, c4 = i & 63;
            uint2 u; u.x = pk2(v.x, v.y); u.y = pk2(v.z, v.w);
            *(uint2*)(clds + row * 512 + ((c4 * 8) ^ ((row & 7) << 4))) = u;
        }
        __syncthreads();
        for (int i = tid; i < 4096; i += 256) {
            int l = i & 63, ks = (i >> 6) & 7, g = i >> 9;
            int r = g * 16 + (l & 15);
            int boff = ks * 64 + (l >> 4) * 16;
            uint4 q = *(const uint4*)(clds + r * 512 + (boff ^ ((r & 7) << 4)));
            ((uint4*)dst)[i] = q;
        }
        return;
    }
    if (bid < 384) {
        // M[c,c'] = sum_d Wq[d,c] Wk[d,c'] ; vectorized j-loop (float4 broadcast)
        int id = bid - 256, h = id >> 4, st = id & 15;
        float* wkL = (float*)clds;                    // [256 d][16 cc]
        for (int i = tid; i < 4096; i += 256) {
            int d = i >> 4, cc = i & 15;
            wkL[i] = Wk[(size_t)h * 65536 + d * 256 + st * 16 + cc];
        }
        __syncthreads();
        const int c = tid;
        float4 a0 = {0,0,0,0}, a1 = {0,0,0,0}, a2 = {0,0,0,0}, a3 = {0,0,0,0};
        const float4* wk4 = (const float4*)wkL;
        #pragma unroll 4
        for (int d = 0; d < 256; ++d) {
            float a = Wq[(size_t)h * 65536 + d * 256 + c];
            float4 k0 = wk4[d*4+0], k1 = wk4[d*4+1], k2 = wk4[d*4+2], k3 = wk4[d*4+3];
            a0.x += a*k0.x; a0.y += a*k0.y; a0.z += a*k0.z; a0.w += a*k0.w;
            a1.x += a*k1.x; a1.y += a*k1.y; a1.z += a*k1.z; a1.w += a*k1.w;
            a2.x += a*k2.x; a2.y += a*k2.y; a2.z += a*k2.z; a2.w += a*k2.w;
            a3.x += a*k3.x; a3.y += a*k3.y; a3.z += a*k3.z; a3.w += a*k3.w;
        }
        float acc[16] = {a0.x,a0.y,a0.z,a0.w, a1.x,a1.y,a1.z,a1.w,
                         a2.x,a2.y,a2.z,a2.w, a3.x,a3.y,a3.z,a3.w};
        char* base = ws + WS_M + (size_t)h * 131072;
        int ks = c >> 5, lgp = (c >> 3) & 3, jb = c & 7;
        #pragma unroll
        for (int j = 0; j < 16; ++j) {
            int cp = st * 16 + j;
            *(unsigned short*)(base + (((st * 8 + ks)) << 10)
                + ((cp & 15) + 16 * lgp) * 16 + jb * 2) = f2bf(acc[j] * 0.0625f);
        }
        return;
    }
    if (bid < 512) {
        // WM[e,c] = sum_d Wp[e,d] Wv_h[d,c] ; Wp stored transposed [256 d][20 pad]
        int id = bid - 384, h = id >> 4, st = id & 15;
        float* wpT2 = (float*)clds;                   // [256][20]
        for (int i = tid; i < 1024; i += 256) {
            int e = i >> 6, d4 = i & 63;
            float4 v = ((const float4*)(Wp + (size_t)(st * 16 + e) * 256))[d4];
            int d = d4 * 4;
            wpT2[(d+0)*20+e] = v.x; wpT2[(d+1)*20+e] = v.y;
            wpT2[(d+2)*20+e] = v.z; wpT2[(d+3)*20+e] = v.w;
        }
        __syncthreads();
        const int c = tid;
        float4 a0 = {0,0,0,0}, a1 = {0,0,0,0}, a2 = {0,0,0,0}, a3 = {0,0,0,0};
        #pragma unroll 4
        for (int d = 0; d < 256; ++d) {
            float wv = Wv[(size_t)h * 65536 + d * 256 + c];
            const float4* wp4 = (const float4*)(wpT2 + d * 20);
            float4 p0 = wp4[0], p1 = wp4[1], p2 = wp4[2], p3 = wp4[3];
            a0.x += wv*p0.x; a0.y += wv*p0.y; a0.z += wv*p0.z; a0.w += wv*p0.w;
            a1.x += wv*p1.x; a1.y += wv*p1.y; a1.z += wv*p1.z; a1.w += wv*p1.w;
            a2.x += wv*p2.x; a2.y += wv*p2.y; a2.z += wv*p2.z; a2.w += wv*p2.w;
            a3.x += wv*p3.x; a3.y += wv*p3.y; a3.z += wv*p3.z; a3.w += wv*p3.w;
        }
        float acc[16] = {a0.x,a0.y,a0.z,a0.w, a1.x,a1.y,a1.z,a1.w,
                         a2.x,a2.y,a2.z,a2.w, a3.x,a3.y,a3.z,a3.w};
        char* base = ws + WS_WM + (size_t)h * 131072;
        int ks = c >> 5, lgp = (c >> 3) & 3, jb = c & 7;
        #pragma unroll
        for (int j = 0; j < 16; ++j) {
            *(unsigned short*)(base + (((st * 8 + ks)) << 10)
                + (j + 16 * lgp) * 16 + jb * 2) = f2bf(acc[j]);
        }
        return;
    }
    if (bid < 520) {
        const int h = bid - 512;
        {
            uint4 z = {0u,0u,0u,0u};
            for (int i = tid; i < 512; i += 256)
                ((uint4*)(ws + WS_WB + (size_t)h * 8192))[i] = z;
        }
        float* tK = (float*)clds;
        float* tQ = (float*)(clds + 16384);
        const int c = tid;
        float s1 = 0.f, s2 = 0.f;
        for (int d0 = 0; d0 < 256; d0 += 16) {
            __syncthreads();
            for (int i = tid; i < 1024; i += 256) {
                int row = i >> 6, c4 = i & 63;
                ((float4*)tK)[row * 64 + c4] =
                    ((const float4*)(Wk + (size_t)h * 65536 + (size_t)(d0 + row) * 256))[c4];
                ((float4*)tQ)[row * 64 + c4] =
                    ((const float4*)(Wq + (size_t)h * 65536 + (size_t)(d0 + row) * 256))[c4];
            }
            __syncthreads();
            #pragma unroll
            for (int dd = 0; dd < 16; ++dd) {
                s1 += tK[dd * 256 + c] * bq[h * 256 + d0 + dd];
                s2 += tQ[dd * 256 + c] * bk[h * 256 + d0 + dd];
            }
        }
        int ks = c >> 5, lgp = (c >> 3) & 3, jb = c & 7;
        char* base = ws + WS_WB + (size_t)h * 8192 + ks * 1024;
        *(unsigned short*)(base + (0 + 16 * lgp) * 16 + jb * 2) = f2bf(s2 * 0.0625f);
        *(unsigned short*)(base + (1 + 16 * lgp) * 16 + jb * 2) = f2bf(s1 * 0.0625f);
        float* red = (float*)(clds + 32768);
        red[tid] = bq[h * 256 + tid] * bk[h * 256 + tid];
        __syncthreads();
        if (tid == 0) {
            float cq = 0.f;
            for (int d = 0; d < 256; ++d) cq += red[d];
            *(float*)(ws + WS_CQ + h * 4) = cq * 0.0625f;
        }
        return;
    }
    {
        const int st = bid - 520;
        float* wpT = (float*)clds;
        float* bvL = (float*)(clds + 17408);
        for (int i = tid; i < 1024; i += 256) {
            int row = i >> 6, c4 = i & 63;
            float4 v = ((const float4*)(Wp + (size_t)(st * 16 + row) * 256))[c4];
            float* dstp = wpT + row * 257 + c4 * 4;
            dstp[0] = v.x; dstp[1] = v.y; dstp[2] = v.z; dstp[3] = v.w;
        }
        for (int i = tid; i < 512; i += 256)
            ((float4*)bvL)[i] = ((const float4*)bv)[i];
        __syncthreads();
        const int el = tid >> 4, dg = tid & 15;
        #pragma unroll
        for (int h = 0; h < 8; ++h) {
            float p = 0.f;
            #pragma unroll
            for (int dd = 0; dd < 16; ++dd) {
                int d = dg * 16 + dd;
                p += bvL[h * 256 + d] * wpT[el * 257 + d];
            }
            p += __shfl_xor(p, 1);
            p += __shfl_xor(p, 2);
            p += __shfl_xor(p, 4);
            p += __shfl_xor(p, 8);
            if (dg == 0)
                *(float*)(ws + WS_BB + (size_t)h * 1024 + (st * 16 + el) * 4)
                    = bp[st * 16 + el] + p;
        }
        return;
    }
}

// =============== main fused kernel: 1024 threads = 16 waves ================
__global__ __launch_bounds__(1024, 1) void mha_fused(
    const char* __restrict__ ws, float* __restrict__ out)
{
    extern __shared__ char lds[];
    const int tid = threadIdx.x;
    const int w  = tid >> 6, l = tid & 63;
    const int lg = l >> 4, lr = l & 15;
    const int mq = w & 7, nh = w >> 3;      // Ph1/Ph3 mapping
    const int bid = blockIdx.x;
    const int xcd = bid & 7, j = bid >> 3;
    const int h = j & 7;
    const int b = ((j >> 3) << 3) | xcd;
    const size_t orow = ((size_t)(h * 256 + b)) * TT;

    const char* Xf  = ws + WS_X  + (size_t)b * 65536;
    const char* Mh  = ws + WS_M  + (size_t)h * 131072;
    const char* WMh = ws + WS_WM + (size_t)h * 131072;
    const char* WBh = ws + WS_WB + (size_t)h * 8192;

    // ---- stage X (64KB, lane-linear frag order) into LDS ----
    {
        const char* src = Xf + tid * 16;
        #pragma unroll
        for (int p = 0; p < 4; ++p)
            __builtin_amdgcn_global_load_lds((glb_u32*)(src + p * 16384),
                (lds_u32*)(lds + LX + tid * 16 + p * 16384), 16, 0, 0);
    }
    VMCNT0(); BAR();

    // ---- Ph0a: [v|u] = X * [w2;w1]^T (nh==0 waves only) ----
    if (nh == 0) {
        f32x4 vacc = f32x4{0.f,0.f,0.f,0.f};
        #pragma unroll
        for (int ks = 0; ks < 8; ++ks) {
            short8 wb = *(const short8*)(WBh + (ks << 10) + l*16);
            short8 xa = *(const short8*)(lds + LX + (((mq*8 + ks)) << 10) + l*16);
            vacc = __builtin_amdgcn_mfma_f32_16x16x32_bf16(xa, wb, vacc, 0, 0, 0);
        }
        if (lr < 2) {
            #pragma unroll
            for (int r = 0; r < 4; ++r) {
                int t = mq*16 + lg*4 + r;
                *(float*)(lds + R_UV + lr*512 + t*4) = vacc[r];
            }
        }
    }

    // ---- Ph0b: T1 = X * N ; wave = (t-half th: 4 t-groups) x (col-pair cp) ----
    {
        const int th = w >> 3, cp = w & 7;    // t-groups th*4..+3, cols {2cp,2cp+1}
        f32x4 acc[4][2];
        #pragma unroll
        for (int i = 0; i < 4; ++i)
            #pragma unroll
            for (int c2 = 0; c2 < 2; ++c2) acc[i][c2] = f32x4{0.f,0.f,0.f,0.f};
        #pragma unroll
        for (int ks = 0; ks < 8; ++ks) {
            short8 nb[2];
            #pragma unroll
            for (int c2 = 0; c2 < 2; ++c2)
                nb[c2] = *(const short8*)(Mh + ((((cp*2+c2)*8 + ks)) << 10) + l*16);
            short8 xa[4];
            #pragma unroll
            for (int i = 0; i < 4; ++i)
                xa[i] = *(const short8*)(lds + LX + ((((th*4+i)*8 + ks)) << 10) + l*16);
            PRIO1();
            #pragma unroll
            for (int i = 0; i < 4; ++i)
                #pragma unroll
                for (int c2 = 0; c2 < 2; ++c2)
                    acc[i][c2] = __builtin_amdgcn_mfma_f32_16x16x32_bf16(xa[i], nb[c2], acc[i][c2], 0, 0, 0);
            PRIO0();
        }
        #pragma unroll
        for (int i = 0; i < 4; ++i)
            #pragma unroll
            for (int c2 = 0; c2 < 2; ++c2)
                #pragma unroll
                for (int r = 0; r < 4; ++r) {
                    int t = (th*4+i)*16 + lg*4 + r;
                    int c = (cp*2+c2)*16 + lr;
                    *(unsigned short*)(lds + LT + t*512 + ((c*2) ^ ((t&7)<<4)))
                        = f2bf(acc[i][c2][r]);
                }
    }
    LGKM0(); BAR();

    // ---- Ph1: S = T1 * X^T ; wave (mq: 16 t, nh: 64 s) ----
    f32x4 sacc[4];
    #pragma unroll
    for (int i = 0; i < 4; ++i) sacc[i] = f32x4{0.f,0.f,0.f,0.f};
    #pragma unroll
    for (int ks2 = 0; ks2 < 8; ++ks2) {
        int t2 = mq*16 + lr;
        short8 ta = *(const short8*)(lds + LT + t2*512 + ((ks2*64 + lg*16) ^ ((t2&7)<<4)));
        short8 sb[4];
        #pragma unroll
        for (int nt = 0; nt < 4; ++nt)
            sb[nt] = *(const short8*)(lds + LX + (((nh*4+nt)*8 + ks2) << 10) + l*16);
        PRIO1();
        #pragma unroll
        for (int nt = 0; nt < 4; ++nt)
            sacc[nt] = __builtin_amdgcn_mfma_f32_16x16x32_bf16(ta, sb[nt], sacc[nt], 0, 0, 0);
        PRIO0();
    }

    // ---- softmax ----
    {
        const float cq = *(const float*)(ws + WS_CQ + h*4);
        float uu[4];
        #pragma unroll
        for (int nt = 0; nt < 4; ++nt)
            uu[nt] = *(const float*)(lds + R_UV + 512 + (nh*64 + nt*16 + lr)*4);
        float* redM = (float*)(lds + R_RED);
        float* redS = redM + 256;
        float rmax[4];
        #pragma unroll
        for (int r = 0; r < 4; ++r) {
            int t = mq*16 + lg*4 + r;
            float vt = *(const float*)(lds + R_UV + t*4) + cq;
            float m = -1e30f;
            #pragma unroll
            for (int nt = 0; nt < 4; ++nt) {
                int s = nh*64 + nt*16 + lr;
                float sv = sacc[nt][r] + vt + uu[nt];
                if (s > t) sv = -1e30f;
                sacc[nt][r] = sv;
                m = fmaxf(m, sv);
            }
            m = fmaxf(m, __shfl_xor(m, 1));
            m = fmaxf(m, __shfl_xor(m, 2));
            m = fmaxf(m, __shfl_xor(m, 4));
            m = fmaxf(m, __shfl_xor(m, 8));
            rmax[r] = m;
        }
        if (lr == 0) {
            #pragma unroll
            for (int r = 0; r < 4; ++r)
                redM[nh*128 + mq*16 + lg*4 + r] = rmax[r];
        }
        LGKM0(); BAR();
        float rsum[4];
        #pragma unroll
        for (int r = 0; r < 4; ++r) {
            int t = mq*16 + lg*4 + r;
            float m = fmaxf(redM[t], redM[128 + t]);
            float ssum = 0.f;
            #pragma unroll
            for (int nt = 0; nt < 4; ++nt) {
                float p = __expf(sacc[nt][r] - m);
                sacc[nt][r] = p;
                ssum += p;
            }
            ssum += __shfl_xor(ssum, 1);
            ssum += __shfl_xor(ssum, 2);
            ssum += __shfl_xor(ssum, 4);
            ssum += __shfl_xor(ssum, 8);
            rsum[r] = ssum;
        }
        if (lr == 0) {
            #pragma unroll
            for (int r = 0; r < 4; ++r)
                redS[nh*128 + mq*16 + lg*4 + r] = rsum[r];
        }
        LGKM0(); BAR();
        #pragma unroll
        for (int r = 0; r < 4; ++r) {
            int t = mq*16 + lg*4 + r;
            float inv = 1.0f / (redS[t] + redS[128 + t]);
            #pragma unroll
            for (int nt = 0; nt < 4; ++nt) {
                int s = nh*64 + nt*16 + lr;
                *(unsigned short*)(lds + LP + t*256 + ((s*2) ^ ((t&7)<<4)))
                    = f2bf(sacc[nt][r] * inv);
            }
        }
    }
    LGKM0(); BAR();

    // P A-frags for this wave's t-group (full 128 s)
    short8 pa[4];
    {
        int t2 = mq*16 + lr;
        #pragma unroll
        for (int ks = 0; ks < 4; ++ks)
            pa[ks] = *(const short8*)(lds + LP + t2*256 + ((ks*64 + lg*16) ^ ((t2&7)<<4)));
    }

    // ---- Ph2/Ph3 per e-half ----
    const float* bbp = (const float*)(ws + WS_BB + h*1024);
    #pragma unroll
    for (int eh = 0; eh < 2; ++eh) {
        // Ph2: Hh = WM[eh rows] * X^T ; wave = (e-pair ep = w&3) x (s-pair sp = w>>2)
        {
            const int ep = w & 3, sp = w >> 2;
            f32x4 acc[2][2];
            #pragma unroll
            for (int i = 0; i < 2; ++i)
                #pragma unroll
                for (int c2 = 0; c2 < 2; ++c2) acc[i][c2] = f32x4{0.f,0.f,0.f,0.f};
            #pragma unroll
            for (int ks = 0; ks < 8; ++ks) {
                short8 wa[2];
                #pragma unroll
                for (int i = 0; i < 2; ++i)
                    wa[i] = *(const short8*)(WMh + ((((eh*8 + ep*2+i)*8 + ks)) << 10) + l*16);
                short8 sb[2];
                #pragma unroll
                for (int c2 = 0; c2 < 2; ++c2)
                    sb[c2] = *(const short8*)(lds + LX + ((((sp*2+c2)*8 + ks)) << 10) + l*16);
                PRIO1();
                #pragma unroll
                for (int i = 0; i < 2; ++i)
                    #pragma unroll
                    for (int c2 = 0; c2 < 2; ++c2)
                        acc[i][c2] = __builtin_amdgcn_mfma_f32_16x16x32_bf16(wa[i], sb[c2], acc[i][c2], 0, 0, 0);
                PRIO0();
            }
            #pragma unroll
            for (int i = 0; i < 2; ++i)
                #pragma unroll
                for (int c2 = 0; c2 < 2; ++c2)
                    #pragma unroll
                    for (int r = 0; r < 4; ++r) {
                        int el = (ep*2+i)*16 + lg*4 + r;
                        int s  = (sp*2+c2)*16 + lr;
                        *(unsigned short*)(lds + LH + el*256 + ((s*2) ^ ((el&7)<<4)))
                            = f2bf(acc[i][c2][r]);
                    }
        }
        LGKM0(); BAR();
        // Ph3: OUT[:, e-half] = P * Hh^T + bb ; wave (t-group mq) x (e nh-half)
        #pragma unroll
        for (int ec = 0; ec < 2; ++ec) {
            f32x4 acc[2];
            acc[0] = f32x4{0.f,0.f,0.f,0.f};
            acc[1] = f32x4{0.f,0.f,0.f,0.f};
            #pragma unroll
            for (int ks = 0; ks < 4; ++ks) {
                short8 hb[2];
                #pragma unroll
                for (int nt = 0; nt < 2; ++nt) {
                    int erl = nh*64 + (ec*2 + nt)*16 + lr;
                    hb[nt] = *(const short8*)(lds + LH + erl*256 + ((ks*64 + lg*16) ^ ((erl&7)<<4)));
                }
                PRIO1();
                #pragma unroll
                for (int nt = 0; nt < 2; ++nt)
                    acc[nt] = __builtin_amdgcn_mfma_f32_16x16x32_bf16(pa[ks], hb[nt], acc[nt], 0, 0, 0);
                PRIO0();
            }
            #pragma unroll
            for (int nt = 0; nt < 2; ++nt) {
                int e = eh*128 + nh*64 + (ec*2 + nt)*16 + lr;
                float bbv = bbp[e];
                #pragma unroll
                for (int r = 0; r < 4; ++r) {
                    int t = mq*16 + lg*4 + r;
                    out[(orow + t) * 256 + e] = acc[nt][r] + bbv;
                }
            }
        }
        if (eh == 0) { LGKM0(); BAR(); }   // protect LH overwrite
    }
}

extern "C" void kernel_launch(void* const* d_in, const int* in_sizes, int n_in,
                              void* d_out, int out_size, void* d_ws, size_t ws_size,
                              hipStream_t stream) {
    (void)in_sizes; (void)n_in; (void)out_size; (void)ws_size; // needs ws_size >= 18948128
    const float* x  = (const float*)d_in[0];
    const float* Wq = (const float*)d_in[1];
    const float* bq = (const float*)d_in[2];
    const float* Wk = (const float*)d_in[3];
    const float* bk = (const float*)d_in[4];
    const float* Wv = (const float*)d_in[5];
    const float* bv = (const float*)d_in[6];
    const float* Wp = (const float*)d_in[7];
    const float* bp = (const float*)d_in[8];
    char* ws = (char*)d_ws;

    hipFuncSetAttribute((const void*)convert_pre,
                        hipFuncAttributeMaxDynamicSharedMemorySize, 65536);
    convert_pre<<<dim3(536), dim3(256), 65536, stream>>>(
        x, Wq, bq, Wk, bk, Wv, bv, Wp, bp, ws);

    hipFuncSetAttribute((const void*)mha_fused,
                        hipFuncAttributeMaxDynamicSharedMemorySize, LDS_SIZE);
    mha_fused<<<dim3(2048), dim3(1024), LDS_SIZE, stream>>>(ws, (float*)d_out);
}

// Round 18
// 232.859 us; speedup vs baseline: 2.8971x; 1.0147x over previous
//
#include <hip/hip_runtime.h>
#include <hip/hip_bf16.h>
#include <stdint.h>

// Fused causal MHA, B=256,T=128,H=8,D=256,C=256. One block per (h,b).
// Round 18: (1) bf16 converts via native __bf16 cast (v_cvt_pk_bf16_f32);
// (2) Ph2-eh0 moved into the softmax-reduce barrier gap (redM->redS);
// (3) convert_pre M/WM d-loops LDS-tiled (kills 256-deep latency chains).

#define TT 128

typedef __attribute__((ext_vector_type(8))) short short8;
typedef __attribute__((ext_vector_type(4))) float f32x4;

// ---- ws map (total 18948128 B < proven-available 20054016) ----
#define WS_X    0u                       // 256 b x 64KB  X A/B-frags
#define WS_M    16777216u                // 8 h x 128KB   M^T-layout B-frags (scaled 1/16)
#define WS_WM   17825792u                // 8 h x 128KB   WM A-frags
#define WS_WB   18874368u                // 8 h x 8KB     [w2;w1] B-frags (rows 0,1), zero-filled
#define WS_BB   18939904u                // 8 h x 1KB     bb fp32
#define WS_CQ   18948096u                // 8 x 4B        cqk fp32

// ---- LDS map (134144 B, 1 block/CU) ----
#define LX     0         // X frags [64KB], lane-linear (staged via global_load_lds)
#define LT     65536     // T1 [128t][512B swz] spans [65536,131072)
#define LP     65536     // after softmax: P [128t][256B swz]
#define LH     98304     // H-half [128e][256B swz] (T1-upper, dead after Ph1)
#define R_UV   131072    // v[128] f32 | u[128] f32
#define R_RED  132096    // redM[256] | redS[256]
#define LDS_SIZE 134144

#define VMCNT0() asm volatile("s_waitcnt vmcnt(0)" ::: "memory")
#define LGKM0()  asm volatile("s_waitcnt lgkmcnt(0)" ::: "memory")
#define BAR()    do { asm volatile("" ::: "memory"); __builtin_amdgcn_s_barrier(); asm volatile("" ::: "memory"); } while (0)
#define PRIO1()  __builtin_amdgcn_s_setprio(1)
#define PRIO0()  __builtin_amdgcn_s_setprio(0)

typedef __attribute__((address_space(3))) uint32_t lds_u32;
typedef __attribute__((address_space(1))) const uint32_t glb_u32;

__device__ __forceinline__ unsigned short f2bf(float x) {
    union { __bf16 b; unsigned short u; } v;
    v.b = (__bf16)x;
    return v.u;
}
__device__ __forceinline__ unsigned pk2(float a, float b) {
    return (unsigned)f2bf(a) | ((unsigned)f2bf(b) << 16);
}

// =============== convert / fold kernel =====================================
__global__ __launch_bounds__(256) void convert_pre(
    const float* __restrict__ x,
    const float* __restrict__ Wq, const float* __restrict__ bq,
    const float* __restrict__ Wk, const float* __restrict__ bk,
    const float* __restrict__ Wv, const float* __restrict__ bv,
    const float* __restrict__ Wp, const float* __restrict__ bp,
    char* __restrict__ ws)
{
    extern __shared__ char clds[];
    const int tid = threadIdx.x;
    const int bid = blockIdx.x;

    if (bid < 256) {
        const float* src = x + (size_t)bid * 32768;
        char* dst = ws + WS_X + (size_t)bid * 65536;
        for (int i = tid; i < 8192; i += 256) {
            float4 v = ((const float4*)src)[i];
            int row = i >> 6, c4 = i & 63;
            uint2 u; u.x = pk2(v.x, v.y); u.y = pk2(v.z, v.w);
            *(uint2*)(clds + row * 512 + ((c4 * 8) ^ ((row & 7) << 4))) = u;
        }
        __syncthreads();
        for (int i = tid; i < 4096; i += 256) {
            int l = i & 63, ks = (i >> 6) & 7, g = i >> 9;
            int r = g * 16 + (l & 15);
            int boff = ks * 64 + (l >> 4) * 16;
            uint4 q = *(const uint4*)(clds + r * 512 + (boff ^ ((r & 7) << 4)));
            ((uint4*)dst)[i] = q;
        }
        return;
    }
    if (bid < 384) {
        // M[c,c'] = sum_d Wq[d,c] Wk[d,c'] ; Wq d-tiles staged in LDS
        int id = bid - 256, h = id >> 4, st = id & 15;
        float* wkL = (float*)clds;                    // [256 d][16 cc] = 16KB
        float* wqT = (float*)(clds + 16384);          // [16][256] staging
        for (int i = tid; i < 4096; i += 256) {
            int d = i >> 4, cc = i & 15;
            wkL[i] = Wk[(size_t)h * 65536 + d * 256 + st * 16 + cc];
        }
        const int c = tid;
        float4 a0 = {0,0,0,0}, a1 = {0,0,0,0}, a2 = {0,0,0,0}, a3 = {0,0,0,0};
        const float4* wk4 = (const float4*)wkL;
        for (int d0 = 0; d0 < 256; d0 += 16) {
            __syncthreads();
            for (int i = tid; i < 1024; i += 256) {
                int row = i >> 6, c4 = i & 63;
                ((float4*)wqT)[row * 64 + c4] =
                    ((const float4*)(Wq + (size_t)h * 65536 + (size_t)(d0 + row) * 256))[c4];
            }
            __syncthreads();
            #pragma unroll
            for (int dd = 0; dd < 16; ++dd) {
                int d = d0 + dd;
                float a = wqT[dd * 256 + c];
                float4 k0 = wk4[d*4+0], k1 = wk4[d*4+1], k2 = wk4[d*4+2], k3 = wk4[d*4+3];
                a0.x += a*k0.x; a0.y += a*k0.y; a0.z += a*k0.z; a0.w += a*k0.w;
                a1.x += a*k1.x; a1.y += a*k1.y; a1.z += a*k1.z; a1.w += a*k1.w;
                a2.x += a*k2.x; a2.y += a*k2.y; a2.z += a*k2.z; a2.w += a*k2.w;
                a3.x += a*k3.x; a3.y += a*k3.y; a3.z += a*k3.z; a3.w += a*k3.w;
            }
        }
        float acc[16] = {a0.x,a0.y,a0.z,a0.w, a1.x,a1.y,a1.z,a1.w,
                         a2.x,a2.y,a2.z,a2.w, a3.x,a3.y,a3.z,a3.w};
        char* base = ws + WS_M + (size_t)h * 131072;
        int ks = c >> 5, lgp = (c >> 3) & 3, jb = c & 7;
        #pragma unroll
        for (int j = 0; j < 16; ++j) {
            int cp = st * 16 + j;
            *(unsigned short*)(base + (((st * 8 + ks)) << 10)
                + ((cp & 15) + 16 * lgp) * 16 + jb * 2) = f2bf(acc[j] * 0.0625f);
        }
        return;
    }
    if (bid < 512) {
        // WM[e,c] = sum_d Wp[e,d] Wv_h[d,c] ; Wp transposed [256][20], Wv tiled
        int id = bid - 384, h = id >> 4, st = id & 15;
        float* wpT2 = (float*)clds;                   // [256][20] = 20480B
        float* wvT  = (float*)(clds + 20480);         // [16][256] staging
        for (int i = tid; i < 1024; i += 256) {
            int e = i >> 6, d4 = i & 63;
            float4 v = ((const float4*)(Wp + (size_t)(st * 16 + e) * 256))[d4];
            int d = d4 * 4;
            wpT2[(d+0)*20+e] = v.x; wpT2[(d+1)*20+e] = v.y;
            wpT2[(d+2)*20+e] = v.z; wpT2[(d+3)*20+e] = v.w;
        }
        const int c = tid;
        float4 a0 = {0,0,0,0}, a1 = {0,0,0,0}, a2 = {0,0,0,0}, a3 = {0,0,0,0};
        for (int d0 = 0; d0 < 256; d0 += 16) {
            __syncthreads();
            for (int i = tid; i < 1024; i += 256) {
                int row = i >> 6, c4 = i & 63;
                ((float4*)wvT)[row * 64 + c4] =
                    ((const float4*)(Wv + (size_t)h * 65536 + (size_t)(d0 + row) * 256))[c4];
            }
            __syncthreads();
            #pragma unroll
            for (int dd = 0; dd < 16; ++dd) {
                int d = d0 + dd;
                float wv = wvT[dd * 256 + c];
                const float4* wp4 = (const float4*)(wpT2 + d * 20);
                float4 p0 = wp4[0], p1 = wp4[1], p2 = wp4[2], p3 = wp4[3];
                a0.x += wv*p0.x; a0.y += wv*p0.y; a0.z += wv*p0.z; a0.w += wv*p0.w;
                a1.x += wv*p1.x; a1.y += wv*p1.y; a1.z += wv*p1.z; a1.w += wv*p1.w;
                a2.x += wv*p2.x; a2.y += wv*p2.y; a2.z += wv*p2.z; a2.w += wv*p2.w;
                a3.x += wv*p3.x; a3.y += wv*p3.y; a3.z += wv*p3.z; a3.w += wv*p3.w;
            }
        }
        float acc[16] = {a0.x,a0.y,a0.z,a0.w, a1.x,a1.y,a1.z,a1.w,
                         a2.x,a2.y,a2.z,a2.w, a3.x,a3.y,a3.z,a3.w};
        char* base = ws + WS_WM + (size_t)h * 131072;
        int ks = c >> 5, lgp = (c >> 3) & 3, jb = c & 7;
        #pragma unroll
        for (int j = 0; j < 16; ++j) {
            *(unsigned short*)(base + (((st * 8 + ks)) << 10)
                + (j + 16 * lgp) * 16 + jb * 2) = f2bf(acc[j]);
        }
        return;
    }
    if (bid < 520) {
        const int h = bid - 512;
        {
            uint4 z = {0u,0u,0u,0u};
            for (int i = tid; i < 512; i += 256)
                ((uint4*)(ws + WS_WB + (size_t)h * 8192))[i] = z;
        }
        float* tK = (float*)clds;
        float* tQ = (float*)(clds + 16384);
        const int c = tid;
        float s1 = 0.f, s2 = 0.f;
        for (int d0 = 0; d0 < 256; d0 += 16) {
            __syncthreads();
            for (int i = tid; i < 1024; i += 256) {
                int row = i >> 6, c4 = i & 63;
                ((float4*)tK)[row * 64 + c4] =
                    ((const float4*)(Wk + (size_t)h * 65536 + (size_t)(d0 + row) * 256))[c4];
                ((float4*)tQ)[row * 64 + c4] =
                    ((const float4*)(Wq + (size_t)h * 65536 + (size_t)(d0 + row) * 256))[c4];
            }
            __syncthreads();
            #pragma unroll
            for (int dd = 0; dd < 16; ++dd) {
                s1 += tK[dd * 256 + c] * bq[h * 256 + d0 + dd];
                s2 += tQ[dd * 256 + c] * bk[h * 256 + d0 + dd];
            }
        }
        int ks = c >> 5, lgp = (c >> 3) & 3, jb = c & 7;
        char* base = ws + WS_WB + (size_t)h * 8192 + ks * 1024;
        *(unsigned short*)(base + (0 + 16 * lgp) * 16 + jb * 2) = f2bf(s2 * 0.0625f);
        *(unsigned short*)(base + (1 + 16 * lgp) * 16 + jb * 2) = f2bf(s1 * 0.0625f);
        float* red = (float*)(clds + 32768);
        red[tid] = bq[h * 256 + tid] * bk[h * 256 + tid];
        __syncthreads();
        if (tid == 0) {
            float cq = 0.f;
            for (int d = 0; d < 256; ++d) cq += red[d];
            *(float*)(ws + WS_CQ + h * 4) = cq * 0.0625f;
        }
        return;
    }
    {
        const int st = bid - 520;
        float* wpT = (float*)clds;
        float* bvL = (float*)(clds + 17408);
        for (int i = tid; i < 1024; i += 256) {
            int row = i >> 6, c4 = i & 63;
            float4 v = ((const float4*)(Wp + (size_t)(st * 16 + row) * 256))[c4];
            float* dstp = wpT + row * 257 + c4 * 4;
            dstp[0] = v.x; dstp[1] = v.y; dstp[2] = v.z; dstp[3] = v.w;
        }
        for (int i = tid; i < 512; i += 256)
            ((float4*)bvL)[i] = ((const float4*)bv)[i];
        __syncthreads();
        const int el = tid >> 4, dg = tid & 15;
        #pragma unroll
        for (int h = 0; h < 8; ++h) {
            float p = 0.f;
            #pragma unroll
            for (int dd = 0; dd < 16; ++dd) {
                int d = dg * 16 + dd;
                p += bvL[h * 256 + d] * wpT[el * 257 + d];
            }
            p += __shfl_xor(p, 1);
            p += __shfl_xor(p, 2);
            p += __shfl_xor(p, 4);
            p += __shfl_xor(p, 8);
            if (dg == 0)
                *(float*)(ws + WS_BB + (size_t)h * 1024 + (st * 16 + el) * 4)
                    = bp[st * 16 + el] + p;
        }
        return;
    }
}

// =============== main fused kernel: 1024 threads = 16 waves ================
__global__ __launch_bounds__(1024, 1) void mha_fused(
    const char* __restrict__ ws, float* __restrict__ out)
{
    extern __shared__ char lds[];
    const int tid = threadIdx.x;
    const int w  = tid >> 6, l = tid & 63;
    const int lg = l >> 4, lr = l & 15;
    const int mq = w & 7, nh = w >> 3;      // Ph1/Ph3 mapping
    const int ep = w & 3, sp = w >> 2;      // Ph2 mapping (2e x 2s tiles)
    const int bid = blockIdx.x;
    const int xcd = bid & 7, j = bid >> 3;
    const int h = j & 7;
    const int b = ((j >> 3) << 3) | xcd;
    const size_t orow = ((size_t)(h * 256 + b)) * TT;

    const char* Xf  = ws + WS_X  + (size_t)b * 65536;
    const char* Mh  = ws + WS_M  + (size_t)h * 131072;
    const char* WMh = ws + WS_WM + (size_t)h * 131072;
    const char* WBh = ws + WS_WB + (size_t)h * 8192;

    // Ph2 sub-kernel: H-half (eh) = WM[eh rows] * X^T -> LH
    auto ph2 = [&](int eh) {
        f32x4 acc[2][2];
        #pragma unroll
        for (int i = 0; i < 2; ++i)
            #pragma unroll
            for (int c2 = 0; c2 < 2; ++c2) acc[i][c2] = f32x4{0.f,0.f,0.f,0.f};
        #pragma unroll
        for (int ks = 0; ks < 8; ++ks) {
            short8 wa[2];
            #pragma unroll
            for (int i = 0; i < 2; ++i)
                wa[i] = *(const short8*)(WMh + ((((eh*8 + ep*2+i)*8 + ks)) << 10) + l*16);
            short8 sb[2];
            #pragma unroll
            for (int c2 = 0; c2 < 2; ++c2)
                sb[c2] = *(const short8*)(lds + LX + ((((sp*2+c2)*8 + ks)) << 10) + l*16);
            PRIO1();
            #pragma unroll
            for (int i = 0; i < 2; ++i)
                #pragma unroll
                for (int c2 = 0; c2 < 2; ++c2)
                    acc[i][c2] = __builtin_amdgcn_mfma_f32_16x16x32_bf16(wa[i], sb[c2], acc[i][c2], 0, 0, 0);
            PRIO0();
        }
        #pragma unroll
        for (int i = 0; i < 2; ++i)
            #pragma unroll
            for (int c2 = 0; c2 < 2; ++c2)
                #pragma unroll
                for (int r = 0; r < 4; ++r) {
                    int el = (ep*2+i)*16 + lg*4 + r;
                    int s  = (sp*2+c2)*16 + lr;
                    *(unsigned short*)(lds + LH + el*256 + ((s*2) ^ ((el&7)<<4)))
                        = f2bf(acc[i][c2][r]);
                }
    };
    // Ph3 sub-kernel: OUT[:, eh half] = P * Hh^T + bb (pa passed in)
    const float* bbp = (const float*)(ws + WS_BB + h*1024);
    auto ph3 = [&](int eh, const short8* pa) {
        #pragma unroll
        for (int ec = 0; ec < 2; ++ec) {
            f32x4 acc[2];
            acc[0] = f32x4{0.f,0.f,0.f,0.f};
            acc[1] = f32x4{0.f,0.f,0.f,0.f};
            #pragma unroll
            for (int ks = 0; ks < 4; ++ks) {
                short8 hb[2];
                #pragma unroll
                for (int nt = 0; nt < 2; ++nt) {
                    int erl = nh*64 + (ec*2 + nt)*16 + lr;
                    hb[nt] = *(const short8*)(lds + LH + erl*256 + ((ks*64 + lg*16) ^ ((erl&7)<<4)));
                }
                PRIO1();
                #pragma unroll
                for (int nt = 0; nt < 2; ++nt)
                    acc[nt] = __builtin_amdgcn_mfma_f32_16x16x32_bf16(pa[ks], hb[nt], acc[nt], 0, 0, 0);
                PRIO0();
            }
            #pragma unroll
            for (int nt = 0; nt < 2; ++nt) {
                int e = eh*128 + nh*64 + (ec*2 + nt)*16 + lr;
                float bbv = bbp[e];
                #pragma unroll
                for (int r = 0; r < 4; ++r) {
                    int t = mq*16 + lg*4 + r;
                    out[(orow + t) * 256 + e] = acc[nt][r] + bbv;
                }
            }
        }
    };

    // ---- stage X (64KB, lane-linear frag order) into LDS ----
    {
        const char* src = Xf + tid * 16;
        #pragma unroll
        for (int p = 0; p < 4; ++p)
            __builtin_amdgcn_global_load_lds((glb_u32*)(src + p * 16384),
                (lds_u32*)(lds + LX + tid * 16 + p * 16384), 16, 0, 0);
    }
    VMCNT0(); BAR();

    // ---- Ph0a: [v|u] = X * [w2;w1]^T (nh==0 waves only) ----
    if (nh == 0) {
        f32x4 vacc = f32x4{0.f,0.f,0.f,0.f};
        #pragma unroll
        for (int ks = 0; ks < 8; ++ks) {
            short8 wb = *(const short8*)(WBh + (ks << 10) + l*16);
            short8 xa = *(const short8*)(lds + LX + (((mq*8 + ks)) << 10) + l*16);
            vacc = __builtin_amdgcn_mfma_f32_16x16x32_bf16(xa, wb, vacc, 0, 0, 0);
        }
        if (lr < 2) {
            #pragma unroll
            for (int r = 0; r < 4; ++r) {
                int t = mq*16 + lg*4 + r;
                *(float*)(lds + R_UV + lr*512 + t*4) = vacc[r];
            }
        }
    }

    // ---- Ph0b: T1 = X * N ; wave = (t-half th) x (col-pair cp) ----
    {
        const int th = w >> 3, cp = w & 7;
        f32x4 acc[4][2];
        #pragma unroll
        for (int i = 0; i < 4; ++i)
            #pragma unroll
            for (int c2 = 0; c2 < 2; ++c2) acc[i][c2] = f32x4{0.f,0.f,0.f,0.f};
        #pragma unroll
        for (int ks = 0; ks < 8; ++ks) {
            short8 nb[2];
            #pragma unroll
            for (int c2 = 0; c2 < 2; ++c2)
                nb[c2] = *(const short8*)(Mh + ((((cp*2+c2)*8 + ks)) << 10) + l*16);
            short8 xa[4];
            #pragma unroll
            for (int i = 0; i < 4; ++i)
                xa[i] = *(const short8*)(lds + LX + ((((th*4+i)*8 + ks)) << 10) + l*16);
            PRIO1();
            #pragma unroll
            for (int i = 0; i < 4; ++i)
                #pragma unroll
                for (int c2 = 0; c2 < 2; ++c2)
                    acc[i][c2] = __builtin_amdgcn_mfma_f32_16x16x32_bf16(xa[i], nb[c2], acc[i][c2], 0, 0, 0);
            PRIO0();
        }
        #pragma unroll
        for (int i = 0; i < 4; ++i)
            #pragma unroll
            for (int c2 = 0; c2 < 2; ++c2)
                #pragma unroll
                for (int r = 0; r < 4; ++r) {
                    int t = (th*4+i)*16 + lg*4 + r;
                    int c = (cp*2+c2)*16 + lr;
                    *(unsigned short*)(lds + LT + t*512 + ((c*2) ^ ((t&7)<<4)))
                        = f2bf(acc[i][c2][r]);
                }
    }
    LGKM0(); BAR();

    // ---- Ph1: S = T1 * X^T ; mask ; rmax -> redM ----
    f32x4 sacc[4];
    #pragma unroll
    for (int i = 0; i < 4; ++i) sacc[i] = f32x4{0.f,0.f,0.f,0.f};
    #pragma unroll
    for (int ks2 = 0; ks2 < 8; ++ks2) {
        int t2 = mq*16 + lr;
        short8 ta = *(const short8*)(lds + LT + t2*512 + ((ks2*64 + lg*16) ^ ((t2&7)<<4)));
        short8 sb[4];
        #pragma unroll
        for (int nt = 0; nt < 4; ++nt)
            sb[nt] = *(const short8*)(lds + LX + (((nh*4+nt)*8 + ks2) << 10) + l*16);
        PRIO1();
        #pragma unroll
        for (int nt = 0; nt < 4; ++nt)
            sacc[nt] = __builtin_amdgcn_mfma_f32_16x16x32_bf16(ta, sb[nt], sacc[nt], 0, 0, 0);
        PRIO0();
    }
    float* redM = (float*)(lds + R_RED);
    float* redS = redM + 256;
    {
        const float cq = *(const float*)(ws + WS_CQ + h*4);
        float uu[4];
        #pragma unroll
        for (int nt = 0; nt < 4; ++nt)
            uu[nt] = *(const float*)(lds + R_UV + 512 + (nh*64 + nt*16 + lr)*4);
        float rmax[4];
        #pragma unroll
        for (int r = 0; r < 4; ++r) {
            int t = mq*16 + lg*4 + r;
            float vt = *(const float*)(lds + R_UV + t*4) + cq;
            float m = -1e30f;
            #pragma unroll
            for (int nt = 0; nt < 4; ++nt) {
                int s = nh*64 + nt*16 + lr;
                float sv = sacc[nt][r] + vt + uu[nt];
                if (s > t) sv = -1e30f;
                sacc[nt][r] = sv;
                m = fmaxf(m, sv);
            }
            m = fmaxf(m, __shfl_xor(m, 1));
            m = fmaxf(m, __shfl_xor(m, 2));
            m = fmaxf(m, __shfl_xor(m, 4));
            m = fmaxf(m, __shfl_xor(m, 8));
            rmax[r] = m;
        }
        if (lr == 0) {
            #pragma unroll
            for (int r = 0; r < 4; ++r)
                redM[nh*128 + mq*16 + lg*4 + r] = rmax[r];
        }
    }
    LGKM0(); BAR();   // T1 reads done (LH writable), redM visible

    // ---- C: Ph2-eh0 (independent MFMA work) + softmax finish (exp/sum) ----
    ph2(0);
    {
        float rsum[4];
        #pragma unroll
        for (int r = 0; r < 4; ++r) {
            int t = mq*16 + lg*4 + r;
            float m = fmaxf(redM[t], redM[128 + t]);
            float ssum = 0.f;
            #pragma unroll
            for (int nt = 0; nt < 4; ++nt) {
                float p = __expf(sacc[nt][r] - m);
                sacc[nt][r] = p;
                ssum += p;
            }
            ssum += __shfl_xor(ssum, 1);
            ssum += __shfl_xor(ssum, 2);
            ssum += __shfl_xor(ssum, 4);
            ssum += __shfl_xor(ssum, 8);
            rsum[r] = ssum;
        }
        if (lr == 0) {
            #pragma unroll
            for (int r = 0; r < 4; ++r)
                redS[nh*128 + mq*16 + lg*4 + r] = rsum[r];
        }
    }
    LGKM0(); BAR();   // redS + LH(eh0) visible

    // ---- E: P -> LP (T1-lower dead) ----
    #pragma unroll
    for (int r = 0; r < 4; ++r) {
        int t = mq*16 + lg*4 + r;
        float inv = 1.0f / (redS[t] + redS[128 + t]);
        #pragma unroll
        for (int nt = 0; nt < 4; ++nt) {
            int s = nh*64 + nt*16 + lr;
            *(unsigned short*)(lds + LP + t*256 + ((s*2) ^ ((t&7)<<4)))
                = f2bf(sacc[nt][r] * inv);
        }
    }
    LGKM0(); BAR();   // P visible

    // ---- G: pa read + Ph3-eh0 ----
    short8 pa[4];
    {
        int t2 = mq*16 + lr;
        #pragma unroll
        for (int ks = 0; ks < 4; ++ks)
            pa[ks] = *(const short8*)(lds + LP + t2*256 + ((ks*64 + lg*16) ^ ((t2&7)<<4)));
    }
    ph3(0, pa);
    LGKM0(); BAR();   // LH reads done

    // ---- I/K: Ph2-eh1 -> Ph3-eh1 ----
    ph2(1);
    LGKM0(); BAR();
    ph3(1, pa);
}

extern "C" void kernel_launch(void* const* d_in, const int* in_sizes, int n_in,
                              void* d_out, int out_size, void* d_ws, size_t ws_size,
                              hipStream_t stream) {
    (void)in_sizes; (void)n_in; (void)out_size; (void)ws_size; // needs ws_size >= 18948128
    const float* x  = (const float*)d_in[0];
    const float* Wq = (const float*)d_in[1];
    const float* bq = (const float*)d_in[2];
    const float* Wk = (const float*)d_in[3];
    const float* bk = (const float*)d_in[4];
    const float* Wv = (const float*)d_in[5];
    const float* bv = (const float*)d_in[6];
    const float* Wp = (const float*)d_in[7];
    const float* bp = (const float*)d_in[8];
    char* ws = (char*)d_ws;

    hipFuncSetAttribute((const void*)convert_pre,
                        hipFuncAttributeMaxDynamicSharedMemorySize, 65536);
    convert_pre<<<dim3(536), dim3(256), 65536, stream>>>(
        x, Wq, bq, Wk, bk, Wv, bv, Wp, bp, ws);

    hipFuncSetAttribute((const void*)mha_fused,
                        hipFuncAttributeMaxDynamicSharedMemorySize, LDS_SIZE);
    mha_fused<<<dim3(2048), dim3(1024), LDS_SIZE, stream>>>(ws, (float*)d_out);
}